// Round 1
// baseline (2097.472 us; speedup 1.0000x reference)
//
#include <hip/hip_runtime.h>
#include <math.h>

#define SEQ 1024
#define BATCH 4
#define DMODEL 512
#define NHEAD 8
#define DK 64
#define DFF 2048
#define U_TOP 34
#define ROWS (BATCH * SEQ)

// ---------------------------------------------------------------------------
// Generic fp32 tiled GEMM: C[M,N] = A[M,K] @ B[K,N] + bias[N], with epilogues.
// MODE 0: bias only. MODE 1: bias + relu. MODE 2: bias, *sqrt(512), + pos-enc.
// Tiles: 64x64 output per block, K-tile 16, 256 threads, 4x4 micro-tile.
// All problem dims here are multiples of the tiles (M=4096, N in {64,512,2048},
// K in {128,512,2048}) so no bounds checks.
// ---------------------------------------------------------------------------
constexpr int TM = 64, TN = 64, TK = 16;

template <int MODE>
__global__ __launch_bounds__(256) void gemm_kernel(
    const float* __restrict__ A, const float* __restrict__ B,
    const float* __restrict__ bias, float* __restrict__ C,
    int M, int N, int K) {
  __shared__ float As[TK][TM + 4];  // transposed A tile, +4 pad (b128-aligned)
  __shared__ float Bs[TK][TN];

  const int tid = threadIdx.x;
  const int tx = tid & 15;   // output col group
  const int ty = tid >> 4;   // output row group
  const int bm = blockIdx.y * TM;
  const int bn = blockIdx.x * TN;

  // A tile load mapping: 64 rows x 4 float4 -> 1 float4/thread
  const int arow = tid >> 2, ac4 = tid & 3;
  // B tile load mapping: 16 rows x 16 float4 -> 1 float4/thread
  const int brow = tid >> 4, bc4 = tid & 15;

  const float* Aload = A + (size_t)(bm + arow) * K + ac4 * 4;
  const float* Bload = B + (size_t)brow * N + bn + bc4 * 4;

  float acc[4][4];
#pragma unroll
  for (int i = 0; i < 4; ++i)
#pragma unroll
    for (int j = 0; j < 4; ++j) acc[i][j] = 0.f;

  for (int k0 = 0; k0 < K; k0 += TK) {
    float4 a4 = *(const float4*)(Aload + k0);
    float4 b4 = *(const float4*)(Bload + (size_t)k0 * N);
    __syncthreads();
    As[ac4 * 4 + 0][arow] = a4.x;
    As[ac4 * 4 + 1][arow] = a4.y;
    As[ac4 * 4 + 2][arow] = a4.z;
    As[ac4 * 4 + 3][arow] = a4.w;
    *(float4*)&Bs[brow][bc4 * 4] = b4;
    __syncthreads();
#pragma unroll
    for (int kk = 0; kk < TK; ++kk) {
      float4 av = *(const float4*)&As[kk][ty * 4];
      float4 bv = *(const float4*)&Bs[kk][tx * 4];
      float a_[4] = {av.x, av.y, av.z, av.w};
      float b_[4] = {bv.x, bv.y, bv.z, bv.w};
#pragma unroll
      for (int i = 0; i < 4; ++i)
#pragma unroll
        for (int j = 0; j < 4; ++j) acc[i][j] += a_[i] * b_[j];
    }
  }

  const float pe_c = (float)(-9.210340371976184 / 512.0);  // -ln(1e4)/d
  const float sqrtd = 22.62741699796952f;                  // sqrt(512)

#pragma unroll
  for (int i = 0; i < 4; ++i) {
    int row = bm + ty * 4 + i;
    float4 o;
    float* op = (float*)&o;
#pragma unroll
    for (int j = 0; j < 4; ++j) {
      int col = bn + tx * 4 + j;
      float v = acc[i][j] + bias[col];
      if (MODE == 1) v = fmaxf(v, 0.f);
      if (MODE == 2) {
        int pos = row & (SEQ - 1);
        float e = expf((float)(col & ~1) * pe_c);
        float arg = (float)pos * e;
        v = v * sqrtd + ((col & 1) ? cosf(arg) : sinf(arg));
      }
      op[j] = v;
    }
    *(float4*)(C + (size_t)row * N + bn + tx * 4) = o;
  }
}

// ---------------------------------------------------------------------------
// Fused residual + LayerNorm: h[row] = LN(h[row] + a[row]) * g + b
// One wave per row (d=512 -> 8 elems/lane), block = 4 waves.
// ---------------------------------------------------------------------------
__global__ __launch_bounds__(256) void ln_kernel(
    float* __restrict__ h, const float* __restrict__ a,
    const float* __restrict__ g, const float* __restrict__ bb) {
  const int row = blockIdx.x * 4 + (threadIdx.x >> 6);
  const int lane = threadIdx.x & 63;
  const size_t base = (size_t)row * DMODEL;
  float v[8];
  float sum = 0.f, sq = 0.f;
#pragma unroll
  for (int i = 0; i < 8; ++i) {
    int col = lane + 64 * i;
    float x = h[base + col] + a[base + col];
    v[i] = x;
    sum += x;
    sq += x * x;
  }
#pragma unroll
  for (int off = 32; off; off >>= 1) {
    sum += __shfl_xor(sum, off);
    sq += __shfl_xor(sq, off);
  }
  float mean = sum * (1.f / 512.f);
  float var = fmaxf(sq * (1.f / 512.f) - mean * mean, 0.f);
  float rstd = 1.f / sqrtf(var + 1e-5f);
#pragma unroll
  for (int i = 0; i < 8; ++i) {
    int col = lane + 64 * i;
    h[base + col] = (v[i] - mean) * rstd * g[col] + bb[col];
  }
}

// ---------------------------------------------------------------------------
// ProbSparse attention, fused per (b, h, 16-query tile).
// Block = 1024 threads. Phase 1: scores (thread-per-key) -> LDS [16][1024].
// Phase 2: one wave per query: exact 34th-largest via 32-bit radix bisection
// on sign-flipped float keys, exp weights, compact (j,w) list, sparse PV.
// Masked entries contribute exp(-10000-m) == 0.0f in fp32 (underflow), so
// skipping them matches the reference exactly.
// ---------------------------------------------------------------------------
#define QT 16

__global__ __launch_bounds__(1024) void attn_kernel(
    const float* __restrict__ Q, const float* __restrict__ K,
    const float* __restrict__ V, float* __restrict__ O) {
  __shared__ float qs[QT][DK];
  __shared__ float s[QT][SEQ];
  __shared__ int jlist[QT][64];
  __shared__ float wlist[QT][64];
  __shared__ int cnt[QT];

  const int tid = threadIdx.x;
  const int q0 = blockIdx.x * QT;
  const int h = blockIdx.y;
  const int b = blockIdx.z;

  // stage Q tile (16 x 64), coalesced
  {
    int qi = tid >> 6, d = tid & 63;
    qs[qi][d] = Q[((size_t)(b * SEQ + q0 + qi)) * DMODEL + h * DK + d];
    if (tid < QT) cnt[tid] = 0;
  }
  __syncthreads();

  // Phase 1: thread tid == key j computes scores for all 16 queries
  {
    const int j = tid;
    const float* kp = K + ((size_t)(b * SEQ + j)) * DMODEL + h * DK;
    float acc[QT];
#pragma unroll
    for (int qi = 0; qi < QT; ++qi) acc[qi] = 0.f;
#pragma unroll
    for (int d4 = 0; d4 < DK / 4; ++d4) {
      float4 k4 = ((const float4*)kp)[d4];
#pragma unroll
      for (int qi = 0; qi < QT; ++qi) {
        float4 q4 = *(const float4*)&qs[qi][d4 * 4];
        acc[qi] += k4.x * q4.x + k4.y * q4.y + k4.z * q4.z + k4.w * q4.w;
      }
    }
#pragma unroll
    for (int qi = 0; qi < QT; ++qi) s[qi][j] = acc[qi] * 0.125f;  // /sqrt(64)
  }
  __syncthreads();

  // Phase 2: wave w handles query w
  {
    const int w = tid >> 6;
    const int lane = tid & 63;
    unsigned key[16];
    float mx = -1e30f;
#pragma unroll
    for (int i = 0; i < 16; ++i) {
      float f = s[w][lane + 64 * i];
      unsigned u = __float_as_uint(f);
      key[i] = (u & 0x80000000u) ? ~u : (u | 0x80000000u);
      mx = fmaxf(mx, f);
    }
#pragma unroll
    for (int off = 32; off; off >>= 1) mx = fmaxf(mx, __shfl_xor(mx, off));

    // radix bisection: largest t with count(key >= t) >= U_TOP  == 34th-largest
    unsigned ans = 0u;
    for (int bit = 31; bit >= 0; --bit) {
      unsigned cand = ans | (1u << bit);
      int c = 0;
#pragma unroll
      for (int i = 0; i < 16; ++i) c += (key[i] >= cand) ? 1 : 0;
#pragma unroll
      for (int off = 32; off; off >>= 1) c += __shfl_xor(c, off);
      if (c >= U_TOP) ans = cand;
    }

    // weights for kept entries; compact into list
    float zsum = 0.f;
#pragma unroll
    for (int i = 0; i < 16; ++i) {
      if (key[i] >= ans) {
        unsigned kk = key[i];
        float f = (kk & 0x80000000u) ? __uint_as_float(kk ^ 0x80000000u)
                                     : __uint_as_float(~kk);
        float e = expf(f - mx);
        zsum += e;
        int idx = atomicAdd(&cnt[w], 1);
        if (idx < 64) {
          jlist[w][idx] = lane + 64 * i;
          wlist[w][idx] = e;
        }
      }
    }
#pragma unroll
    for (int off = 32; off; off >>= 1) zsum += __shfl_xor(zsum, off);

    // sparse PV: lane == output dim d
    int n = cnt[w];
    n = n < 64 ? n : 64;
    float o = 0.f;
    const float* vbase = V + (size_t)b * SEQ * DMODEL + h * DK;
    for (int i = 0; i < n; ++i) {
      int j = jlist[w][i];
      float wj = wlist[w][i];
      o += wj * vbase[(size_t)j * DMODEL + lane];
    }
    o /= zsum;
    O[((size_t)(b * SEQ + q0 + w)) * DMODEL + h * DK + lane] = o;
  }
}

// ---------------------------------------------------------------------------
// Orchestration
// ---------------------------------------------------------------------------
extern "C" void kernel_launch(void* const* d_in, const int* in_sizes, int n_in,
                              void* d_out, int out_size, void* d_ws,
                              size_t ws_size, hipStream_t stream) {
  const float* x = (const float*)d_in[0];
  const float* W_emb = (const float*)d_in[1];
  const float* b_emb = (const float*)d_in[2];
  const float* Wq = (const float*)d_in[3];
  const float* bq = (const float*)d_in[4];
  const float* Wk = (const float*)d_in[5];
  const float* bk = (const float*)d_in[6];
  const float* Wv = (const float*)d_in[7];
  const float* bv = (const float*)d_in[8];
  const float* Wo = (const float*)d_in[9];
  const float* bo = (const float*)d_in[10];
  const float* ln1_g = (const float*)d_in[11];
  const float* ln1_b = (const float*)d_in[12];
  const float* W1 = (const float*)d_in[13];
  const float* b1 = (const float*)d_in[14];
  const float* W2 = (const float*)d_in[15];
  const float* b2 = (const float*)d_in[16];
  const float* ln2_g = (const float*)d_in[17];
  const float* ln2_b = (const float*)d_in[18];
  const float* W_dec = (const float*)d_in[19];
  const float* b_dec = (const float*)d_in[20];

  float* ws = (float*)d_ws;
  const size_t M1 = (size_t)ROWS * DMODEL;  // 2M floats
  float* h = ws;
  float* q = ws + 2 * M1 - M1;  // keep simple explicit offsets below
  // layout: [h | q | k | v | ao | t1], ffh reuses q..ao (8M floats)
  q = ws + M1;
  float* k = ws + 2 * M1;
  float* v = ws + 3 * M1;
  float* ao = ws + 4 * M1;
  float* t1 = ws + 5 * M1;
  float* ffh = q;  // 4096 x 2048 spans q,k,v,ao

  dim3 blk(256);
  // embed: h = (x @ W_emb + b_emb)*sqrt(d) + PE
  gemm_kernel<2><<<dim3(DMODEL / TN, ROWS / TM), blk, 0, stream>>>(
      x, W_emb, b_emb, h, ROWS, DMODEL, 128);

  for (int i = 0; i < 3; ++i) {
    const size_t wsz = (size_t)DMODEL * DMODEL;
    const float* Wq_i = Wq + i * wsz;
    const float* Wk_i = Wk + i * wsz;
    const float* Wv_i = Wv + i * wsz;
    const float* Wo_i = Wo + i * wsz;
    const float* W1_i = W1 + (size_t)i * DMODEL * DFF;
    const float* W2_i = W2 + (size_t)i * DFF * DMODEL;

    gemm_kernel<0><<<dim3(DMODEL / TN, ROWS / TM), blk, 0, stream>>>(
        h, Wq_i, bq + i * DMODEL, q, ROWS, DMODEL, DMODEL);
    gemm_kernel<0><<<dim3(DMODEL / TN, ROWS / TM), blk, 0, stream>>>(
        h, Wk_i, bk + i * DMODEL, k, ROWS, DMODEL, DMODEL);
    gemm_kernel<0><<<dim3(DMODEL / TN, ROWS / TM), blk, 0, stream>>>(
        h, Wv_i, bv + i * DMODEL, v, ROWS, DMODEL, DMODEL);

    attn_kernel<<<dim3(SEQ / QT, NHEAD, BATCH), dim3(1024), 0, stream>>>(
        q, k, v, ao);

    gemm_kernel<0><<<dim3(DMODEL / TN, ROWS / TM), blk, 0, stream>>>(
        ao, Wo_i, bo + i * DMODEL, t1, ROWS, DMODEL, DMODEL);
    ln_kernel<<<dim3(ROWS / 4), blk, 0, stream>>>(h, t1, ln1_g + i * DMODEL,
                                                  ln1_b + i * DMODEL);

    gemm_kernel<1><<<dim3(DFF / TN, ROWS / TM), blk, 0, stream>>>(
        h, W1_i, b1 + i * DFF, ffh, ROWS, DFF, DMODEL);
    gemm_kernel<0><<<dim3(DMODEL / TN, ROWS / TM), blk, 0, stream>>>(
        ffh, W2_i, b2 + i * DMODEL, t1, ROWS, DMODEL, DFF);
    ln_kernel<<<dim3(ROWS / 4), blk, 0, stream>>>(h, t1, ln2_g + i * DMODEL,
                                                  ln2_b + i * DMODEL);
  }

  gemm_kernel<0><<<dim3(64 / TN, ROWS / TM), blk, 0, stream>>>(
      h, W_dec, b_dec, (float*)d_out, ROWS, 64, DMODEL);
}

// Round 2
// 1080.338 us; speedup vs baseline: 1.9415x; 1.9415x over previous
//
#include <hip/hip_runtime.h>
#include <math.h>

#define SEQ 1024
#define BATCH 4
#define DMODEL 512
#define NHEAD 8
#define DK 64
#define DFF 2048
#define U_TOP 34
#define ROWS (BATCH * SEQ)

typedef unsigned short ushort_t;
typedef __attribute__((ext_vector_type(8))) short short8;
typedef __attribute__((ext_vector_type(4))) float float4v;

__device__ inline ushort_t f2bf(float f) {
  unsigned u = __float_as_uint(f);
  unsigned r = u + 0x7fffu + ((u >> 16) & 1u);
  return (ushort_t)(r >> 16);
}
__device__ inline float bf2f(ushort_t u) {
  return __uint_as_float((unsigned)u << 16);
}

__device__ inline void glds16(const void* g, void* l) {
  __builtin_amdgcn_global_load_lds(
      (const __attribute__((address_space(1))) unsigned int*)g,
      (__attribute__((address_space(3))) unsigned int*)l, 16, 0, 0);
}

// ---------------------------------------------------------------------------
// fp32 tiled GEMM (embed + decoder only). MODE 0: bias. MODE 2: bias,
// *sqrt(512), + positional encoding.
// ---------------------------------------------------------------------------
constexpr int TM = 64, TN = 64, TK = 16;

template <int MODE>
__global__ __launch_bounds__(256) void gemm_kernel(
    const float* __restrict__ A, const float* __restrict__ B,
    const float* __restrict__ bias, float* __restrict__ C,
    int M, int N, int K) {
  __shared__ float As[TK][TM + 4];
  __shared__ float Bs[TK][TN];

  const int tid = threadIdx.x;
  const int tx = tid & 15;
  const int ty = tid >> 4;
  const int bm = blockIdx.y * TM;
  const int bn = blockIdx.x * TN;

  const int arow = tid >> 2, ac4 = tid & 3;
  const int brow = tid >> 4, bc4 = tid & 15;

  const float* Aload = A + (size_t)(bm + arow) * K + ac4 * 4;
  const float* Bload = B + (size_t)brow * N + bn + bc4 * 4;

  float acc[4][4];
#pragma unroll
  for (int i = 0; i < 4; ++i)
#pragma unroll
    for (int j = 0; j < 4; ++j) acc[i][j] = 0.f;

  for (int k0 = 0; k0 < K; k0 += TK) {
    float4 a4 = *(const float4*)(Aload + k0);
    float4 b4 = *(const float4*)(Bload + (size_t)k0 * N);
    __syncthreads();
    As[ac4 * 4 + 0][arow] = a4.x;
    As[ac4 * 4 + 1][arow] = a4.y;
    As[ac4 * 4 + 2][arow] = a4.z;
    As[ac4 * 4 + 3][arow] = a4.w;
    *(float4*)&Bs[brow][bc4 * 4] = b4;
    __syncthreads();
#pragma unroll
    for (int kk = 0; kk < TK; ++kk) {
      float4 av = *(const float4*)&As[kk][ty * 4];
      float4 bv = *(const float4*)&Bs[kk][tx * 4];
      float a_[4] = {av.x, av.y, av.z, av.w};
      float b_[4] = {bv.x, bv.y, bv.z, bv.w};
#pragma unroll
      for (int i = 0; i < 4; ++i)
#pragma unroll
        for (int j = 0; j < 4; ++j) acc[i][j] += a_[i] * b_[j];
    }
  }

  const float pe_c = (float)(-9.210340371976184 / 512.0);
  const float sqrtd = 22.62741699796952f;

#pragma unroll
  for (int i = 0; i < 4; ++i) {
    int row = bm + ty * 4 + i;
    float4 o;
    float* op = (float*)&o;
#pragma unroll
    for (int j = 0; j < 4; ++j) {
      int col = bn + tx * 4 + j;
      float v = acc[i][j] + bias[col];
      if (MODE == 2) {
        int pos = row & (SEQ - 1);
        float e = expf((float)(col & ~1) * pe_c);
        float arg = (float)pos * e;
        v = v * sqrtd + ((col & 1) ? cosf(arg) : sinf(arg));
      }
      op[j] = v;
    }
    *(float4*)(C + (size_t)row * N + bn + tx * 4) = o;
  }
}

// ---------------------------------------------------------------------------
// bf16 MFMA GEMM (m97 structure): C[M,N] = A[M,K] @ Bt[N,K]^T + bias.
// 128x128 tile, BK=32, 256 threads = 2x2 waves, 4x4 16x16x32 MFMAs per wave.
// A, Bt are bf16 (raw u16/i16); bias fp32; out fp32 or bf16 (+optional relu).
// grid.z batches weight matrices (QKV): Bt += z*zWstride, C += z*zCstride.
// ---------------------------------------------------------------------------
template <int RELU, int OUTBF16>
__global__ __launch_bounds__(256) void gemm_mfma(
    const ushort_t* __restrict__ A, const short* __restrict__ Bt,
    const float* __restrict__ b0, const float* __restrict__ b1,
    const float* __restrict__ b2, void* __restrict__ Cout,
    int K, int N, int zWstride, int zCstride) {
  __shared__ short As[128 * 32];
  __shared__ short Bs[128 * 32];

  const int tid = threadIdx.x;
  const int lane = tid & 63, w = tid >> 6;
  const int wm = w >> 1, wn = w & 1;
  const int quad = lane >> 4, r16 = lane & 15;
  const int bm = blockIdx.y * 128, bn = blockIdx.x * 128;
  const int z = blockIdx.z;
  const short* Bz = Bt + (size_t)z * zWstride;
  const float* bias = (z == 0) ? b0 : (z == 1 ? b1 : b2);

  // staging mapping: lane l -> row (l/4), 16B k-segment (l%4)
  const int arow = lane >> 2, akseg = lane & 3;
  const ushort_t* Ag0 = A + (size_t)(bm + w * 16 + arow) * K + akseg * 8;
  const ushort_t* Ag1 = Ag0 + (size_t)64 * K;
  const short* Bg0 = Bz + (size_t)(bn + w * 16 + arow) * K + akseg * 8;
  const short* Bg1 = Bg0 + (size_t)64 * K;
  short* lA0 = As + (w * 16) * 32;
  short* lA1 = As + (64 + w * 16) * 32;
  short* lB0 = Bs + (w * 16) * 32;
  short* lB1 = Bs + (64 + w * 16) * 32;

  float4v acc[4][4];
#pragma unroll
  for (int m = 0; m < 4; ++m)
#pragma unroll
    for (int n = 0; n < 4; ++n) acc[m][n] = (float4v){0.f, 0.f, 0.f, 0.f};

  for (int k0 = 0; k0 < K; k0 += 32) {
    __syncthreads();  // prev iter's ds_reads done before overwrite
    glds16(Ag0 + k0, lA0);
    glds16(Ag1 + k0, lA1);
    glds16(Bg0 + k0, lB0);
    glds16(Bg1 + k0, lB1);
    __syncthreads();  // drains vmcnt: staged data visible

    short8 af[4], bfr[4];
#pragma unroll
    for (int m = 0; m < 4; ++m)
      af[m] = *(const short8*)&As[(wm * 64 + m * 16 + r16) * 32 + quad * 8];
#pragma unroll
    for (int n = 0; n < 4; ++n)
      bfr[n] = *(const short8*)&Bs[(wn * 64 + n * 16 + r16) * 32 + quad * 8];
#pragma unroll
    for (int m = 0; m < 4; ++m)
#pragma unroll
      for (int n = 0; n < 4; ++n)
        acc[m][n] = __builtin_amdgcn_mfma_f32_16x16x32_bf16(af[m], bfr[n],
                                                            acc[m][n], 0, 0, 0);
  }

  float bias_n[4];
#pragma unroll
  for (int n = 0; n < 4; ++n) bias_n[n] = bias[bn + wn * 64 + n * 16 + r16];

#pragma unroll
  for (int m = 0; m < 4; ++m) {
#pragma unroll
    for (int n = 0; n < 4; ++n) {
      int col = bn + wn * 64 + n * 16 + r16;
#pragma unroll
      for (int reg = 0; reg < 4; ++reg) {
        int row = bm + wm * 64 + m * 16 + quad * 4 + reg;
        float v = acc[m][n][reg] + bias_n[n];
        if (RELU) v = fmaxf(v, 0.f);
        if (OUTBF16) {
          ushort_t* C = (ushort_t*)Cout + (size_t)z * zCstride;
          C[(size_t)row * N + col] = f2bf(v);
        } else {
          float* C = (float*)Cout + (size_t)z * zCstride;
          C[(size_t)row * N + col] = v;
        }
      }
    }
  }
}

// ---------------------------------------------------------------------------
// Weight convert+transpose: W[K][N] f32 -> Wt[N][K] bf16, all 6 weights of one
// layer in one launch. 32x32 tiles via LDS. Offsets (elements) in wt region:
// WqT 0, WkT 262144, WvT 524288, WoT 786432, W1T 1048576, W2T 2097152.
// ---------------------------------------------------------------------------
__global__ __launch_bounds__(256) void convert_weights(
    const float* __restrict__ Wq, const float* __restrict__ Wk,
    const float* __restrict__ Wv, const float* __restrict__ Wo,
    const float* __restrict__ W1, const float* __restrict__ W2,
    short* __restrict__ wt) {
  __shared__ float t[32][33];
  const int id = blockIdx.x;
  const float* src;
  short* dst;
  int K, N, tk, tn;
  if (id < 1024) {
    int wi = id >> 8, tile = id & 255;
    src = (wi == 0) ? Wq : (wi == 1) ? Wk : (wi == 2) ? Wv : Wo;
    dst = wt + wi * 262144;
    K = 512; N = 512; tk = tile >> 4; tn = tile & 15;
  } else if (id < 2048) {
    int tile = id - 1024;
    src = W1; dst = wt + 1048576;
    K = 512; N = 2048; tk = tile >> 6; tn = tile & 63;
  } else {
    int tile = id - 2048;
    src = W2; dst = wt + 2097152;
    K = 2048; N = 512; tk = tile >> 4; tn = tile & 15;
  }
  const int k0 = tk * 32, n0 = tn * 32;
  const int tx = threadIdx.x, ty = threadIdx.y;
#pragma unroll
  for (int i = 0; i < 4; ++i) {
    int r = ty + i * 8;
    t[r][tx] = src[(size_t)(k0 + r) * N + n0 + tx];
  }
  __syncthreads();
#pragma unroll
  for (int i = 0; i < 4; ++i) {
    int r = ty + i * 8;
    dst[(size_t)(n0 + r) * K + k0 + tx] = (short)f2bf(t[tx][r]);
  }
}

// fp32 -> bf16 elementwise (post-embed h), 4 elements/thread
__global__ __launch_bounds__(256) void f32_to_bf16_kernel(
    const float* __restrict__ src, ushort_t* __restrict__ dst) {
  int i = blockIdx.x * blockDim.x + threadIdx.x;
  float4 v = ((const float4*)src)[i];
  ushort4 o;
  o.x = f2bf(v.x); o.y = f2bf(v.y); o.z = f2bf(v.z); o.w = f2bf(v.w);
  ((ushort4*)dst)[i] = o;
}

// ---------------------------------------------------------------------------
// Fused residual + LayerNorm; writes fp32 h and bf16 mirror hb.
// ---------------------------------------------------------------------------
__global__ __launch_bounds__(256) void ln_kernel(
    float* __restrict__ h, const float* __restrict__ a,
    const float* __restrict__ g, const float* __restrict__ bb,
    ushort_t* __restrict__ hb) {
  const int row = blockIdx.x * 4 + (threadIdx.x >> 6);
  const int lane = threadIdx.x & 63;
  const size_t base = (size_t)row * DMODEL;
  float v[8];
  float sum = 0.f, sq = 0.f;
#pragma unroll
  for (int i = 0; i < 8; ++i) {
    int col = lane + 64 * i;
    float x = h[base + col] + a[base + col];
    v[i] = x;
    sum += x;
    sq += x * x;
  }
#pragma unroll
  for (int off = 32; off; off >>= 1) {
    sum += __shfl_xor(sum, off);
    sq += __shfl_xor(sq, off);
  }
  float mean = sum * (1.f / 512.f);
  float var = fmaxf(sq * (1.f / 512.f) - mean * mean, 0.f);
  float rstd = 1.f / sqrtf(var + 1e-5f);
#pragma unroll
  for (int i = 0; i < 8; ++i) {
    int col = lane + 64 * i;
    float y = (v[i] - mean) * rstd * g[col] + bb[col];
    h[base + col] = y;
    hb[base + col] = f2bf(y);
  }
}

// ---------------------------------------------------------------------------
// ProbSparse attention (bf16 in/out, fp32 scores + exact top-34 selection).
// ---------------------------------------------------------------------------
#define QT 16

__global__ __launch_bounds__(1024) void attn_kernel(
    const ushort_t* __restrict__ Qb, const ushort_t* __restrict__ Kb,
    const ushort_t* __restrict__ Vb, ushort_t* __restrict__ Ob) {
  __shared__ float qs[QT][DK];
  __shared__ float s[QT][SEQ];
  __shared__ int jlist[QT][64];
  __shared__ float wlist[QT][64];
  __shared__ int cnt[QT];

  const int tid = threadIdx.x;
  const int q0 = blockIdx.x * QT;
  const int h = blockIdx.y;
  const int b = blockIdx.z;

  {
    int qi = tid >> 6, d = tid & 63;
    qs[qi][d] = bf2f(Qb[((size_t)(b * SEQ + q0 + qi)) * DMODEL + h * DK + d]);
    if (tid < QT) cnt[tid] = 0;
  }
  __syncthreads();

  // Phase 1: thread = key j; scores for all 16 queries
  {
    const int j = tid;
    const ushort_t* kp = Kb + ((size_t)(b * SEQ + j)) * DMODEL + h * DK;
    float acc[QT];
#pragma unroll
    for (int qi = 0; qi < QT; ++qi) acc[qi] = 0.f;
#pragma unroll
    for (int c = 0; c < 8; ++c) {
      uint4 raw = ((const uint4*)kp)[c];
      float kf[8];
      kf[0] = bf2f((ushort_t)(raw.x & 0xffff));
      kf[1] = bf2f((ushort_t)(raw.x >> 16));
      kf[2] = bf2f((ushort_t)(raw.y & 0xffff));
      kf[3] = bf2f((ushort_t)(raw.y >> 16));
      kf[4] = bf2f((ushort_t)(raw.z & 0xffff));
      kf[5] = bf2f((ushort_t)(raw.z >> 16));
      kf[6] = bf2f((ushort_t)(raw.w & 0xffff));
      kf[7] = bf2f((ushort_t)(raw.w >> 16));
#pragma unroll
      for (int qi = 0; qi < QT; ++qi) {
        float4 qa = *(const float4*)&qs[qi][c * 8];
        float4 qb2 = *(const float4*)&qs[qi][c * 8 + 4];
        acc[qi] += kf[0] * qa.x + kf[1] * qa.y + kf[2] * qa.z + kf[3] * qa.w +
                   kf[4] * qb2.x + kf[5] * qb2.y + kf[6] * qb2.z + kf[7] * qb2.w;
      }
    }
#pragma unroll
    for (int qi = 0; qi < QT; ++qi) s[qi][j] = acc[qi] * 0.125f;
  }
  __syncthreads();

  // Phase 2: wave w handles query w
  {
    const int w = tid >> 6;
    const int lane = tid & 63;
    unsigned key[16];
    float mx = -1e30f;
#pragma unroll
    for (int i = 0; i < 16; ++i) {
      float f = s[w][lane + 64 * i];
      unsigned u = __float_as_uint(f);
      key[i] = (u & 0x80000000u) ? ~u : (u | 0x80000000u);
      mx = fmaxf(mx, f);
    }
#pragma unroll
    for (int off = 32; off; off >>= 1) mx = fmaxf(mx, __shfl_xor(mx, off));

    unsigned ans = 0u;
    for (int bit = 31; bit >= 0; --bit) {
      unsigned cand = ans | (1u << bit);
      int c = 0;
#pragma unroll
      for (int i = 0; i < 16; ++i) c += (key[i] >= cand) ? 1 : 0;
#pragma unroll
      for (int off = 32; off; off >>= 1) c += __shfl_xor(c, off);
      if (c >= U_TOP) ans = cand;
    }

    float zsum = 0.f;
#pragma unroll
    for (int i = 0; i < 16; ++i) {
      if (key[i] >= ans) {
        unsigned kk = key[i];
        float f = (kk & 0x80000000u) ? __uint_as_float(kk ^ 0x80000000u)
                                     : __uint_as_float(~kk);
        float e = expf(f - mx);
        zsum += e;
        int idx = atomicAdd(&cnt[w], 1);
        if (idx < 64) {
          jlist[w][idx] = lane + 64 * i;
          wlist[w][idx] = e;
        }
      }
    }
#pragma unroll
    for (int off = 32; off; off >>= 1) zsum += __shfl_xor(zsum, off);

    int n = cnt[w];
    n = n < 64 ? n : 64;
    float o = 0.f;
    const ushort_t* vbase = Vb + (size_t)b * SEQ * DMODEL + h * DK;
    for (int i = 0; i < n; ++i) {
      int j = jlist[w][i];
      float wj = wlist[w][i];
      o += wj * bf2f(vbase[(size_t)j * DMODEL + lane]);
    }
    o /= zsum;
    Ob[((size_t)(b * SEQ + q0 + w)) * DMODEL + h * DK + lane] = f2bf(o);
  }
}

// ---------------------------------------------------------------------------
// Orchestration
// ---------------------------------------------------------------------------
extern "C" void kernel_launch(void* const* d_in, const int* in_sizes, int n_in,
                              void* d_out, int out_size, void* d_ws,
                              size_t ws_size, hipStream_t stream) {
  const float* x = (const float*)d_in[0];
  const float* W_emb = (const float*)d_in[1];
  const float* b_emb = (const float*)d_in[2];
  const float* Wq = (const float*)d_in[3];
  const float* bq = (const float*)d_in[4];
  const float* Wk = (const float*)d_in[5];
  const float* bk = (const float*)d_in[6];
  const float* Wv = (const float*)d_in[7];
  const float* bv = (const float*)d_in[8];
  const float* Wo = (const float*)d_in[9];
  const float* bo = (const float*)d_in[10];
  const float* ln1_g = (const float*)d_in[11];
  const float* ln1_b = (const float*)d_in[12];
  const float* W1 = (const float*)d_in[13];
  const float* b1 = (const float*)d_in[14];
  const float* W2 = (const float*)d_in[15];
  const float* b2 = (const float*)d_in[16];
  const float* ln2_g = (const float*)d_in[17];
  const float* ln2_b = (const float*)d_in[18];
  const float* W_dec = (const float*)d_in[19];
  const float* b_dec = (const float*)d_in[20];

  // ws layout (bytes): [0,8M) h f32 | [8M,20M) qkv bf16 (ffh bf16 [8M,24M)
  // reuses it) | [24M,28M) ao bf16 | [28M,36M) t1 f32 | [36M,40M) hb bf16 |
  // [40M,~46.3M) wt bf16 transposed weights.  Total < 48MB (proven budget).
  char* wsb = (char*)d_ws;
  float* h = (float*)wsb;
  ushort_t* qkv = (ushort_t*)(wsb + ((size_t)8 << 20));
  ushort_t* ffh = (ushort_t*)(wsb + ((size_t)8 << 20));
  ushort_t* ao = (ushort_t*)(wsb + ((size_t)24 << 20));
  float* t1 = (float*)(wsb + ((size_t)28 << 20));
  ushort_t* hb = (ushort_t*)(wsb + ((size_t)36 << 20));
  short* wt = (short*)(wsb + ((size_t)40 << 20));

  const size_t M1 = (size_t)ROWS * DMODEL;  // 2097152

  // embed (fp32) + PE, then bf16 mirror
  gemm_kernel<2><<<dim3(DMODEL / TN, ROWS / TM), 256, 0, stream>>>(
      x, W_emb, b_emb, h, ROWS, DMODEL, 128);
  f32_to_bf16_kernel<<<dim3((int)(M1 / 4 / 256)), 256, 0, stream>>>(h, hb);

  for (int i = 0; i < 3; ++i) {
    const size_t wsz = (size_t)DMODEL * DMODEL;
    convert_weights<<<dim3(3072), dim3(32, 8), 0, stream>>>(
        Wq + i * wsz, Wk + i * wsz, Wv + i * wsz, Wo + i * wsz,
        W1 + (size_t)i * DMODEL * DFF, W2 + (size_t)i * DFF * DMODEL, wt);

    // QKV batched: z=0,1,2
    gemm_mfma<0, 1><<<dim3(4, 32, 3), 256, 0, stream>>>(
        hb, wt, bq + i * DMODEL, bk + i * DMODEL, bv + i * DMODEL, (void*)qkv,
        512, 512, 262144, 2097152);

    attn_kernel<<<dim3(SEQ / QT, NHEAD, BATCH), dim3(1024), 0, stream>>>(
        qkv, qkv + 2097152, qkv + 4194304, ao);

    gemm_mfma<0, 0><<<dim3(4, 32, 1), 256, 0, stream>>>(
        ao, wt + 786432, bo + i * DMODEL, bo + i * DMODEL, bo + i * DMODEL,
        (void*)t1, 512, 512, 0, 0);
    ln_kernel<<<dim3(ROWS / 4), 256, 0, stream>>>(
        h, t1, ln1_g + i * DMODEL, ln1_b + i * DMODEL, hb);

    gemm_mfma<1, 1><<<dim3(16, 32, 1), 256, 0, stream>>>(
        hb, wt + 1048576, b1 + i * DFF, b1 + i * DFF, b1 + i * DFF, (void*)ffh,
        512, 2048, 0, 0);
    gemm_mfma<0, 0><<<dim3(4, 32, 1), 256, 0, stream>>>(
        ffh, wt + 2097152, b2 + i * DMODEL, b2 + i * DMODEL, b2 + i * DMODEL,
        (void*)t1, 2048, 512, 0, 0);
    ln_kernel<<<dim3(ROWS / 4), 256, 0, stream>>>(
        h, t1, ln2_g + i * DMODEL, ln2_b + i * DMODEL, hb);
  }

  gemm_kernel<0><<<dim3(64 / TN, ROWS / TM), 256, 0, stream>>>(
      h, W_dec, b_dec, (float*)d_out, ROWS, 64, DMODEL);
}

// Round 3
// 791.058 us; speedup vs baseline: 2.6515x; 1.3657x over previous
//
#include <hip/hip_runtime.h>
#include <math.h>

#define SEQ 1024
#define BATCH 4
#define DMODEL 512
#define NHEAD 8
#define DK 64
#define DFF 2048
#define U_TOP 34
#define ROWS (BATCH * SEQ)

typedef unsigned short ushort_t;
typedef __attribute__((ext_vector_type(8))) short short8;
typedef __attribute__((ext_vector_type(4))) float float4v;

__device__ inline ushort_t f2bf(float f) {
  unsigned u = __float_as_uint(f);
  unsigned r = u + 0x7fffu + ((u >> 16) & 1u);
  return (ushort_t)(r >> 16);
}
__device__ inline float bf2f(ushort_t u) {
  return __uint_as_float((unsigned)u << 16);
}

__device__ inline void glds16(const void* g, void* l) {
  __builtin_amdgcn_global_load_lds(
      (const __attribute__((address_space(1))) unsigned int*)g,
      (__attribute__((address_space(3))) unsigned int*)l, 16, 0, 0);
}

// ---------------------------------------------------------------------------
// fp32 tiled GEMM (embed + decoder only). MODE 0: bias. MODE 2: bias,
// *sqrt(512), + positional encoding.
// ---------------------------------------------------------------------------
constexpr int TM = 64, TN = 64, TK = 16;

template <int MODE>
__global__ __launch_bounds__(256) void gemm_kernel(
    const float* __restrict__ A, const float* __restrict__ B,
    const float* __restrict__ bias, float* __restrict__ C,
    int M, int N, int K) {
  __shared__ float As[TK][TM + 4];
  __shared__ float Bs[TK][TN];

  const int tid = threadIdx.x;
  const int tx = tid & 15;
  const int ty = tid >> 4;
  const int bm = blockIdx.y * TM;
  const int bn = blockIdx.x * TN;

  const int arow = tid >> 2, ac4 = tid & 3;
  const int brow = tid >> 4, bc4 = tid & 15;

  const float* Aload = A + (size_t)(bm + arow) * K + ac4 * 4;
  const float* Bload = B + (size_t)brow * N + bn + bc4 * 4;

  float acc[4][4];
#pragma unroll
  for (int i = 0; i < 4; ++i)
#pragma unroll
    for (int j = 0; j < 4; ++j) acc[i][j] = 0.f;

  for (int k0 = 0; k0 < K; k0 += TK) {
    float4 a4 = *(const float4*)(Aload + k0);
    float4 b4 = *(const float4*)(Bload + (size_t)k0 * N);
    __syncthreads();
    As[ac4 * 4 + 0][arow] = a4.x;
    As[ac4 * 4 + 1][arow] = a4.y;
    As[ac4 * 4 + 2][arow] = a4.z;
    As[ac4 * 4 + 3][arow] = a4.w;
    *(float4*)&Bs[brow][bc4 * 4] = b4;
    __syncthreads();
#pragma unroll
    for (int kk = 0; kk < TK; ++kk) {
      float4 av = *(const float4*)&As[kk][ty * 4];
      float4 bv = *(const float4*)&Bs[kk][tx * 4];
      float a_[4] = {av.x, av.y, av.z, av.w};
      float b_[4] = {bv.x, bv.y, bv.z, bv.w};
#pragma unroll
      for (int i = 0; i < 4; ++i)
#pragma unroll
        for (int j = 0; j < 4; ++j) acc[i][j] += a_[i] * b_[j];
    }
  }

  const float pe_c = (float)(-9.210340371976184 / 512.0);
  const float sqrtd = 22.62741699796952f;

#pragma unroll
  for (int i = 0; i < 4; ++i) {
    int row = bm + ty * 4 + i;
    float4 o;
    float* op = (float*)&o;
#pragma unroll
    for (int j = 0; j < 4; ++j) {
      int col = bn + tx * 4 + j;
      float v = acc[i][j] + bias[col];
      if (MODE == 2) {
        int pos = row & (SEQ - 1);
        float e = expf((float)(col & ~1) * pe_c);
        float arg = (float)pos * e;
        v = v * sqrtd + ((col & 1) ? cosf(arg) : sinf(arg));
      }
      op[j] = v;
    }
    *(float4*)(C + (size_t)row * N + bn + tx * 4) = o;
  }
}

// ---------------------------------------------------------------------------
// bf16 MFMA GEMM (m97 structure): C[M,N] = A[M,K] @ Bt[N,K]^T + bias.
// ---------------------------------------------------------------------------
template <int RELU, int OUTBF16>
__global__ __launch_bounds__(256) void gemm_mfma(
    const ushort_t* __restrict__ A, const short* __restrict__ Bt,
    const float* __restrict__ b0, const float* __restrict__ b1,
    const float* __restrict__ b2, void* __restrict__ Cout,
    int K, int N, int zWstride, int zCstride) {
  __shared__ short As[128 * 32];
  __shared__ short Bs[128 * 32];

  const int tid = threadIdx.x;
  const int lane = tid & 63, w = tid >> 6;
  const int wm = w >> 1, wn = w & 1;
  const int quad = lane >> 4, r16 = lane & 15;
  const int bm = blockIdx.y * 128, bn = blockIdx.x * 128;
  const int z = blockIdx.z;
  const short* Bz = Bt + (size_t)z * zWstride;
  const float* bias = (z == 0) ? b0 : (z == 1 ? b1 : b2);

  const int arow = lane >> 2, akseg = lane & 3;
  const ushort_t* Ag0 = A + (size_t)(bm + w * 16 + arow) * K + akseg * 8;
  const ushort_t* Ag1 = Ag0 + (size_t)64 * K;
  const short* Bg0 = Bz + (size_t)(bn + w * 16 + arow) * K + akseg * 8;
  const short* Bg1 = Bg0 + (size_t)64 * K;
  short* lA0 = As + (w * 16) * 32;
  short* lA1 = As + (64 + w * 16) * 32;
  short* lB0 = Bs + (w * 16) * 32;
  short* lB1 = Bs + (64 + w * 16) * 32;

  float4v acc[4][4];
#pragma unroll
  for (int m = 0; m < 4; ++m)
#pragma unroll
    for (int n = 0; n < 4; ++n) acc[m][n] = (float4v){0.f, 0.f, 0.f, 0.f};

  for (int k0 = 0; k0 < K; k0 += 32) {
    __syncthreads();
    glds16(Ag0 + k0, lA0);
    glds16(Ag1 + k0, lA1);
    glds16(Bg0 + k0, lB0);
    glds16(Bg1 + k0, lB1);
    __syncthreads();

    short8 af[4], bfr[4];
#pragma unroll
    for (int m = 0; m < 4; ++m)
      af[m] = *(const short8*)&As[(wm * 64 + m * 16 + r16) * 32 + quad * 8];
#pragma unroll
    for (int n = 0; n < 4; ++n)
      bfr[n] = *(const short8*)&Bs[(wn * 64 + n * 16 + r16) * 32 + quad * 8];
#pragma unroll
    for (int m = 0; m < 4; ++m)
#pragma unroll
      for (int n = 0; n < 4; ++n)
        acc[m][n] = __builtin_amdgcn_mfma_f32_16x16x32_bf16(af[m], bfr[n],
                                                            acc[m][n], 0, 0, 0);
  }

  float bias_n[4];
#pragma unroll
  for (int n = 0; n < 4; ++n) bias_n[n] = bias[bn + wn * 64 + n * 16 + r16];

#pragma unroll
  for (int m = 0; m < 4; ++m) {
#pragma unroll
    for (int n = 0; n < 4; ++n) {
      int col = bn + wn * 64 + n * 16 + r16;
#pragma unroll
      for (int reg = 0; reg < 4; ++reg) {
        int row = bm + wm * 64 + m * 16 + quad * 4 + reg;
        float v = acc[m][n][reg] + bias_n[n];
        if (RELU) v = fmaxf(v, 0.f);
        if (OUTBF16) {
          ushort_t* C = (ushort_t*)Cout + (size_t)z * zCstride;
          C[(size_t)row * N + col] = f2bf(v);
        } else {
          float* C = (float*)Cout + (size_t)z * zCstride;
          C[(size_t)row * N + col] = v;
        }
      }
    }
  }
}

// ---------------------------------------------------------------------------
// Weight convert+transpose: W[K][N] f32 -> Wt[N][K] bf16 (6 weights/layer).
// ---------------------------------------------------------------------------
__global__ __launch_bounds__(256) void convert_weights(
    const float* __restrict__ Wq, const float* __restrict__ Wk,
    const float* __restrict__ Wv, const float* __restrict__ Wo,
    const float* __restrict__ W1, const float* __restrict__ W2,
    short* __restrict__ wt) {
  __shared__ float t[32][33];
  const int id = blockIdx.x;
  const float* src;
  short* dst;
  int K, N, tk, tn;
  if (id < 1024) {
    int wi = id >> 8, tile = id & 255;
    src = (wi == 0) ? Wq : (wi == 1) ? Wk : (wi == 2) ? Wv : Wo;
    dst = wt + wi * 262144;
    K = 512; N = 512; tk = tile >> 4; tn = tile & 15;
  } else if (id < 2048) {
    int tile = id - 1024;
    src = W1; dst = wt + 1048576;
    K = 512; N = 2048; tk = tile >> 6; tn = tile & 63;
  } else {
    int tile = id - 2048;
    src = W2; dst = wt + 2097152;
    K = 2048; N = 512; tk = tile >> 4; tn = tile & 15;
  }
  const int k0 = tk * 32, n0 = tn * 32;
  const int tx = threadIdx.x, ty = threadIdx.y;
#pragma unroll
  for (int i = 0; i < 4; ++i) {
    int r = ty + i * 8;
    t[r][tx] = src[(size_t)(k0 + r) * N + n0 + tx];
  }
  __syncthreads();
#pragma unroll
  for (int i = 0; i < 4; ++i) {
    int r = ty + i * 8;
    dst[(size_t)(n0 + r) * K + k0 + tx] = (short)f2bf(t[tx][r]);
  }
}

__global__ __launch_bounds__(256) void f32_to_bf16_kernel(
    const float* __restrict__ src, ushort_t* __restrict__ dst) {
  int i = blockIdx.x * blockDim.x + threadIdx.x;
  float4 v = ((const float4*)src)[i];
  ushort4 o;
  o.x = f2bf(v.x); o.y = f2bf(v.y); o.z = f2bf(v.z); o.w = f2bf(v.w);
  ((ushort4*)dst)[i] = o;
}

// ---------------------------------------------------------------------------
// Fused residual + LayerNorm; writes fp32 h and bf16 mirror hb.
// ---------------------------------------------------------------------------
__global__ __launch_bounds__(256) void ln_kernel(
    float* __restrict__ h, const float* __restrict__ a,
    const float* __restrict__ g, const float* __restrict__ bb,
    ushort_t* __restrict__ hb) {
  const int row = blockIdx.x * 4 + (threadIdx.x >> 6);
  const int lane = threadIdx.x & 63;
  const size_t base = (size_t)row * DMODEL;
  float v[8];
  float sum = 0.f, sq = 0.f;
#pragma unroll
  for (int i = 0; i < 8; ++i) {
    int col = lane + 64 * i;
    float x = h[base + col] + a[base + col];
    v[i] = x;
    sum += x;
    sq += x * x;
  }
#pragma unroll
  for (int off = 32; off; off >>= 1) {
    sum += __shfl_xor(sum, off);
    sq += __shfl_xor(sq, off);
  }
  float mean = sum * (1.f / 512.f);
  float var = fmaxf(sq * (1.f / 512.f) - mean * mean, 0.f);
  float rstd = 1.f / sqrtf(var + 1e-5f);
#pragma unroll
  for (int i = 0; i < 8; ++i) {
    int col = lane + 64 * i;
    float y = (v[i] - mean) * rstd * g[col] + bb[col];
    h[base + col] = y;
    hb[base + col] = f2bf(y);
  }
}

// ---------------------------------------------------------------------------
// ProbSparse attention v2.
// Block = 1024 threads = 16 waves per (b, h, 16-query tile).
// Phase 1 (MFMA): wave w computes S[16 queries][64 keys j0=64w] via 8x
//   mfma_f32_16x16x32_bf16, fragments loaded straight from global (A row-major
//   16B segments). C-layout (col=lane&15, row=quad*4+reg) stored to LDS
//   s[16][1028] (stride 1028 floats: 16B-aligned, 4*1028 % 32 == 16 so quad
//   stores are free 2-way bank aliases).
// Phase 2: wave w owns query w; lane owns scores j in [16*lane, 16*lane+16)
//   (4x ds_read_b128). Exact 34th-largest via 32-bit radix bisection with
//   __ballot counting (VALU cmp + SALU popcount). Compaction via ballot
//   prefix-sum (no atomics). Sparse PV over kept entries.
// ---------------------------------------------------------------------------
#define SSTR 1028

__global__ __launch_bounds__(1024) void attn_kernel(
    const ushort_t* __restrict__ Qb, const ushort_t* __restrict__ Kb,
    const ushort_t* __restrict__ Vb, ushort_t* __restrict__ Ob) {
  __shared__ float s[16 * SSTR];
  __shared__ int jlist[16][64];
  __shared__ float wlist[16][64];
  __shared__ int ntot[16];

  const int tid = threadIdx.x;
  const int q0 = blockIdx.x * 16;
  const int h = blockIdx.y;
  const int b = blockIdx.z;
  const int w = tid >> 6;
  const int lane = tid & 63;
  const int quad = lane >> 4, r16 = lane & 15;

  // ---- Phase 1: MFMA scores ----
  {
    const int j0 = w * 64;
    const ushort_t* qrow =
        Qb + (size_t)(b * SEQ + q0 + r16) * DMODEL + h * DK + quad * 8;
    short8 aq0 = *(const short8*)qrow;
    short8 aq1 = *(const short8*)(qrow + 32);

    float4v acc[4];
#pragma unroll
    for (int nt = 0; nt < 4; ++nt) {
      const ushort_t* krow =
          Kb + (size_t)(b * SEQ + j0 + nt * 16 + r16) * DMODEL + h * DK +
          quad * 8;
      short8 bk0 = *(const short8*)krow;
      short8 bk1 = *(const short8*)(krow + 32);
      float4v a = (float4v){0.f, 0.f, 0.f, 0.f};
      a = __builtin_amdgcn_mfma_f32_16x16x32_bf16(aq0, bk0, a, 0, 0, 0);
      a = __builtin_amdgcn_mfma_f32_16x16x32_bf16(aq1, bk1, a, 0, 0, 0);
      acc[nt] = a;
    }
#pragma unroll
    for (int nt = 0; nt < 4; ++nt)
#pragma unroll
      for (int reg = 0; reg < 4; ++reg)
        s[(quad * 4 + reg) * SSTR + j0 + nt * 16 + r16] =
            acc[nt][reg] * 0.125f;
  }
  __syncthreads();

  // ---- Phase 2: selection + softmax + sparse PV (wave w = query q0+w) ----
  {
    float v[16];
#pragma unroll
    for (int c = 0; c < 4; ++c) {
      float4 t = *(const float4*)&s[w * SSTR + lane * 16 + c * 4];
      v[c * 4 + 0] = t.x; v[c * 4 + 1] = t.y;
      v[c * 4 + 2] = t.z; v[c * 4 + 3] = t.w;
    }
    unsigned key[16];
    float mx = -1e30f;
#pragma unroll
    for (int i = 0; i < 16; ++i) {
      unsigned u = __float_as_uint(v[i]);
      key[i] = (u & 0x80000000u) ? ~u : (u | 0x80000000u);
      mx = fmaxf(mx, v[i]);
    }
#pragma unroll
    for (int off = 32; off; off >>= 1) mx = fmaxf(mx, __shfl_xor(mx, off));

    // radix bisection with ballot counting
    unsigned ans = 0u;
    for (int bit = 31; bit >= 0; --bit) {
      unsigned cand = ans | (1u << bit);
      int c = 0;
#pragma unroll
      for (int i = 0; i < 16; ++i)
        c += (int)__popcll(__ballot(key[i] >= cand));
      if (c >= U_TOP) ans = cand;
    }

    // compaction via ballot prefix-sum
    const unsigned long long lmask_lt = (1ull << lane) - 1ull;
    int total = 0;
    float zsum = 0.f;
#pragma unroll
    for (int i = 0; i < 16; ++i) {
      bool keep = key[i] >= ans;
      unsigned long long mask = __ballot(keep);
      if (keep) {
        float e = __expf(v[i] - mx);
        zsum += e;
        int pos = total + (int)__popcll(mask & lmask_lt);
        if (pos < 64) {
          jlist[w][pos] = lane * 16 + i;
          wlist[w][pos] = e;
        }
      }
      total += (int)__popcll(mask);
    }
#pragma unroll
    for (int off = 32; off; off >>= 1) zsum += __shfl_xor(zsum, off);
    if (lane == 0) ntot[w] = total < 64 ? total : 64;
  }
  __syncthreads();

  {
    int n = ntot[w];
    float o = 0.f;
    const ushort_t* vbase = Vb + (size_t)b * SEQ * DMODEL + h * DK;
    float zs = 0.f;
    // zsum recompute from wlist would lose ties>64; redo reduction cheaply:
    for (int i = 0; i < n; ++i) zs += wlist[w][i];
    for (int i = 0; i < n; ++i) {
      int j = jlist[w][i];
      float wj = wlist[w][i];
      o += wj * bf2f(vbase[(size_t)j * DMODEL + lane]);
    }
    o /= zs;
    Ob[(size_t)(b * SEQ + q0 + w) * DMODEL + h * DK + lane] = f2bf(o);
  }
}

// ---------------------------------------------------------------------------
// Orchestration
// ---------------------------------------------------------------------------
extern "C" void kernel_launch(void* const* d_in, const int* in_sizes, int n_in,
                              void* d_out, int out_size, void* d_ws,
                              size_t ws_size, hipStream_t stream) {
  const float* x = (const float*)d_in[0];
  const float* W_emb = (const float*)d_in[1];
  const float* b_emb = (const float*)d_in[2];
  const float* Wq = (const float*)d_in[3];
  const float* bq = (const float*)d_in[4];
  const float* Wk = (const float*)d_in[5];
  const float* bk = (const float*)d_in[6];
  const float* Wv = (const float*)d_in[7];
  const float* bv = (const float*)d_in[8];
  const float* Wo = (const float*)d_in[9];
  const float* bo = (const float*)d_in[10];
  const float* ln1_g = (const float*)d_in[11];
  const float* ln1_b = (const float*)d_in[12];
  const float* W1 = (const float*)d_in[13];
  const float* b1 = (const float*)d_in[14];
  const float* W2 = (const float*)d_in[15];
  const float* b2 = (const float*)d_in[16];
  const float* ln2_g = (const float*)d_in[17];
  const float* ln2_b = (const float*)d_in[18];
  const float* W_dec = (const float*)d_in[19];
  const float* b_dec = (const float*)d_in[20];

  char* wsb = (char*)d_ws;
  float* h = (float*)wsb;
  ushort_t* qkv = (ushort_t*)(wsb + ((size_t)8 << 20));
  ushort_t* ffh = (ushort_t*)(wsb + ((size_t)8 << 20));
  ushort_t* ao = (ushort_t*)(wsb + ((size_t)24 << 20));
  float* t1 = (float*)(wsb + ((size_t)28 << 20));
  ushort_t* hb = (ushort_t*)(wsb + ((size_t)36 << 20));
  short* wt = (short*)(wsb + ((size_t)40 << 20));

  const size_t M1 = (size_t)ROWS * DMODEL;

  gemm_kernel<2><<<dim3(DMODEL / TN, ROWS / TM), 256, 0, stream>>>(
      x, W_emb, b_emb, h, ROWS, DMODEL, 128);
  f32_to_bf16_kernel<<<dim3((int)(M1 / 4 / 256)), 256, 0, stream>>>(h, hb);

  for (int i = 0; i < 3; ++i) {
    const size_t wsz = (size_t)DMODEL * DMODEL;
    convert_weights<<<dim3(3072), dim3(32, 8), 0, stream>>>(
        Wq + i * wsz, Wk + i * wsz, Wv + i * wsz, Wo + i * wsz,
        W1 + (size_t)i * DMODEL * DFF, W2 + (size_t)i * DFF * DMODEL, wt);

    gemm_mfma<0, 1><<<dim3(4, 32, 3), 256, 0, stream>>>(
        hb, wt, bq + i * DMODEL, bk + i * DMODEL, bv + i * DMODEL, (void*)qkv,
        512, 512, 262144, 2097152);

    attn_kernel<<<dim3(SEQ / 16, NHEAD, BATCH), dim3(1024), 0, stream>>>(
        qkv, qkv + 2097152, qkv + 4194304, ao);

    gemm_mfma<0, 0><<<dim3(4, 32, 1), 256, 0, stream>>>(
        ao, wt + 786432, bo + i * DMODEL, bo + i * DMODEL, bo + i * DMODEL,
        (void*)t1, 512, 512, 0, 0);
    ln_kernel<<<dim3(ROWS / 4), 256, 0, stream>>>(
        h, t1, ln1_g + i * DMODEL, ln1_b + i * DMODEL, hb);

    gemm_mfma<1, 1><<<dim3(16, 32, 1), 256, 0, stream>>>(
        hb, wt + 1048576, b1 + i * DFF, b1 + i * DFF, b1 + i * DFF, (void*)ffh,
        512, 2048, 0, 0);
    gemm_mfma<0, 0><<<dim3(4, 32, 1), 256, 0, stream>>>(
        ffh, wt + 2097152, b2 + i * DMODEL, b2 + i * DMODEL, b2 + i * DMODEL,
        (void*)t1, 2048, 512, 0, 0);
    ln_kernel<<<dim3(ROWS / 4), 256, 0, stream>>>(
        h, t1, ln2_g + i * DMODEL, ln2_b + i * DMODEL, hb);
  }

  gemm_kernel<0><<<dim3(64 / TN, ROWS / TM), 256, 0, stream>>>(
      h, W_dec, b_dec, (float*)d_out, ROWS, 64, DMODEL);
}

// Round 4
// 683.539 us; speedup vs baseline: 3.0685x; 1.1573x over previous
//
#include <hip/hip_runtime.h>
#include <math.h>

#define SEQ 1024
#define BATCH 4
#define DMODEL 512
#define NHEAD 8
#define DK 64
#define DFF 2048
#define U_TOP 34
#define ROWS (BATCH * SEQ)

typedef unsigned short ushort_t;
typedef __attribute__((ext_vector_type(8))) short short8;
typedef __attribute__((ext_vector_type(4))) float float4v;

__device__ inline ushort_t f2bf(float f) {
  unsigned u = __float_as_uint(f);
  unsigned r = u + 0x7fffu + ((u >> 16) & 1u);
  return (ushort_t)(r >> 16);
}
__device__ inline float bf2f(ushort_t u) {
  return __uint_as_float((unsigned)u << 16);
}

__device__ inline void glds16(const void* g, void* l) {
  __builtin_amdgcn_global_load_lds(
      (const __attribute__((address_space(1))) unsigned int*)g,
      (__attribute__((address_space(3))) unsigned int*)l, 16, 0, 0);
}

// ---------------------------------------------------------------------------
// fp32 tiled GEMM (embed + decoder only). MODE 0: bias. MODE 2: bias,
// *sqrt(512), + positional encoding.
// ---------------------------------------------------------------------------
constexpr int TM = 64, TN = 64, TK = 16;

template <int MODE>
__global__ __launch_bounds__(256) void gemm_kernel(
    const float* __restrict__ A, const float* __restrict__ B,
    const float* __restrict__ bias, float* __restrict__ C,
    int M, int N, int K) {
  __shared__ float As[TK][TM + 4];
  __shared__ float Bs[TK][TN];

  const int tid = threadIdx.x;
  const int tx = tid & 15;
  const int ty = tid >> 4;
  const int bm = blockIdx.y * TM;
  const int bn = blockIdx.x * TN;

  const int arow = tid >> 2, ac4 = tid & 3;
  const int brow = tid >> 4, bc4 = tid & 15;

  const float* Aload = A + (size_t)(bm + arow) * K + ac4 * 4;
  const float* Bload = B + (size_t)brow * N + bn + bc4 * 4;

  float acc[4][4];
#pragma unroll
  for (int i = 0; i < 4; ++i)
#pragma unroll
    for (int j = 0; j < 4; ++j) acc[i][j] = 0.f;

  for (int k0 = 0; k0 < K; k0 += TK) {
    float4 a4 = *(const float4*)(Aload + k0);
    float4 b4 = *(const float4*)(Bload + (size_t)k0 * N);
    __syncthreads();
    As[ac4 * 4 + 0][arow] = a4.x;
    As[ac4 * 4 + 1][arow] = a4.y;
    As[ac4 * 4 + 2][arow] = a4.z;
    As[ac4 * 4 + 3][arow] = a4.w;
    *(float4*)&Bs[brow][bc4 * 4] = b4;
    __syncthreads();
#pragma unroll
    for (int kk = 0; kk < TK; ++kk) {
      float4 av = *(const float4*)&As[kk][ty * 4];
      float4 bv = *(const float4*)&Bs[kk][tx * 4];
      float a_[4] = {av.x, av.y, av.z, av.w};
      float b_[4] = {bv.x, bv.y, bv.z, bv.w};
#pragma unroll
      for (int i = 0; i < 4; ++i)
#pragma unroll
        for (int j = 0; j < 4; ++j) acc[i][j] += a_[i] * b_[j];
    }
  }

  const float pe_c = (float)(-9.210340371976184 / 512.0);
  const float sqrtd = 22.62741699796952f;

#pragma unroll
  for (int i = 0; i < 4; ++i) {
    int row = bm + ty * 4 + i;
    float4 o;
    float* op = (float*)&o;
#pragma unroll
    for (int j = 0; j < 4; ++j) {
      int col = bn + tx * 4 + j;
      float v = acc[i][j] + bias[col];
      if (MODE == 2) {
        int pos = row & (SEQ - 1);
        float e = expf((float)(col & ~1) * pe_c);
        float arg = (float)pos * e;
        v = v * sqrtd + ((col & 1) ? cosf(arg) : sinf(arg));
      }
      op[j] = v;
    }
    *(float4*)(C + (size_t)row * N + bn + tx * 4) = o;
  }
}

// ---------------------------------------------------------------------------
// bf16 MFMA GEMM, tile 128(M) x 64(N), BK=32, 256 threads = 2x2 waves.
// Wave covers 64 rows x 32 cols = 4 m-tiles x 2 n-tiles of 16x16x32 MFMA.
// 12 KB LDS -> high blocks/CU; grids >= 256 blocks for all N=512 GEMMs.
// C = A[M,K] @ Bt[N,K]^T + bias; z batches weights (QKV).
// ---------------------------------------------------------------------------
template <int RELU, int OUTBF16>
__global__ __launch_bounds__(256) void gemm_mfma(
    const ushort_t* __restrict__ A, const short* __restrict__ Bt,
    const float* __restrict__ b0, const float* __restrict__ b1,
    const float* __restrict__ b2, void* __restrict__ Cout,
    int K, int N, int zWstride, int zCstride) {
  __shared__ short As[128 * 32];  // 8 KB
  __shared__ short Bs[64 * 32];   // 4 KB

  const int tid = threadIdx.x;
  const int lane = tid & 63, w = tid >> 6;
  const int wm = w >> 1, wn = w & 1;
  const int quad = lane >> 4, r16 = lane & 15;
  const int bm = blockIdx.y * 128, bn = blockIdx.x * 64;
  const int z = blockIdx.z;
  const short* Bz = Bt + (size_t)z * zWstride;
  const float* bias = (z == 0) ? b0 : (z == 1 ? b1 : b2);

  // staging: lane l -> row l/4, 16B k-seg l%4 (16 rows per glds)
  const int srow = lane >> 2, skseg = lane & 3;
  const ushort_t* Ag0 = A + (size_t)(bm + w * 32 + srow) * K + skseg * 8;
  const ushort_t* Ag1 = Ag0 + (size_t)16 * K;
  const short* Bg0 = Bz + (size_t)(bn + w * 16 + srow) * K + skseg * 8;
  short* lA0 = As + (w * 32) * 32;
  short* lA1 = As + (w * 32 + 16) * 32;
  short* lB0 = Bs + (w * 16) * 32;

  float4v acc[4][2];
#pragma unroll
  for (int m = 0; m < 4; ++m)
#pragma unroll
    for (int n = 0; n < 2; ++n) acc[m][n] = (float4v){0.f, 0.f, 0.f, 0.f};

  for (int k0 = 0; k0 < K; k0 += 32) {
    __syncthreads();
    glds16(Ag0 + k0, lA0);
    glds16(Ag1 + k0, lA1);
    glds16(Bg0 + k0, lB0);
    __syncthreads();

    short8 af[4], bfr[2];
#pragma unroll
    for (int m = 0; m < 4; ++m)
      af[m] = *(const short8*)&As[(wm * 64 + m * 16 + r16) * 32 + quad * 8];
#pragma unroll
    for (int n = 0; n < 2; ++n)
      bfr[n] = *(const short8*)&Bs[(wn * 32 + n * 16 + r16) * 32 + quad * 8];
#pragma unroll
    for (int m = 0; m < 4; ++m)
#pragma unroll
      for (int n = 0; n < 2; ++n)
        acc[m][n] = __builtin_amdgcn_mfma_f32_16x16x32_bf16(af[m], bfr[n],
                                                            acc[m][n], 0, 0, 0);
  }

  float bias_n[2];
#pragma unroll
  for (int n = 0; n < 2; ++n) bias_n[n] = bias[bn + wn * 32 + n * 16 + r16];

#pragma unroll
  for (int m = 0; m < 4; ++m) {
#pragma unroll
    for (int n = 0; n < 2; ++n) {
      int col = bn + wn * 32 + n * 16 + r16;
#pragma unroll
      for (int reg = 0; reg < 4; ++reg) {
        int row = bm + wm * 64 + m * 16 + quad * 4 + reg;
        float v = acc[m][n][reg] + bias_n[n];
        if (RELU) v = fmaxf(v, 0.f);
        if (OUTBF16) {
          ushort_t* C = (ushort_t*)Cout + (size_t)z * zCstride;
          C[(size_t)row * N + col] = f2bf(v);
        } else {
          float* C = (float*)Cout + (size_t)z * zCstride;
          C[(size_t)row * N + col] = v;
        }
      }
    }
  }
}

// ---------------------------------------------------------------------------
// Weight convert+transpose: W[K][N] f32 -> Wt[N][K] bf16 (6 weights/layer).
// ---------------------------------------------------------------------------
__global__ __launch_bounds__(256) void convert_weights(
    const float* __restrict__ Wq, const float* __restrict__ Wk,
    const float* __restrict__ Wv, const float* __restrict__ Wo,
    const float* __restrict__ W1, const float* __restrict__ W2,
    short* __restrict__ wt) {
  __shared__ float t[32][33];
  const int id = blockIdx.x;
  const float* src;
  short* dst;
  int K, N, tk, tn;
  if (id < 1024) {
    int wi = id >> 8, tile = id & 255;
    src = (wi == 0) ? Wq : (wi == 1) ? Wk : (wi == 2) ? Wv : Wo;
    dst = wt + wi * 262144;
    K = 512; N = 512; tk = tile >> 4; tn = tile & 15;
  } else if (id < 2048) {
    int tile = id - 1024;
    src = W1; dst = wt + 1048576;
    K = 512; N = 2048; tk = tile >> 6; tn = tile & 63;
  } else {
    int tile = id - 2048;
    src = W2; dst = wt + 2097152;
    K = 2048; N = 512; tk = tile >> 4; tn = tile & 15;
  }
  const int k0 = tk * 32, n0 = tn * 32;
  const int tx = threadIdx.x, ty = threadIdx.y;
#pragma unroll
  for (int i = 0; i < 4; ++i) {
    int r = ty + i * 8;
    t[r][tx] = src[(size_t)(k0 + r) * N + n0 + tx];
  }
  __syncthreads();
#pragma unroll
  for (int i = 0; i < 4; ++i) {
    int r = ty + i * 8;
    dst[(size_t)(n0 + r) * K + k0 + tx] = (short)f2bf(t[tx][r]);
  }
}

__global__ __launch_bounds__(256) void f32_to_bf16_kernel(
    const float* __restrict__ src, ushort_t* __restrict__ dst) {
  int i = blockIdx.x * blockDim.x + threadIdx.x;
  float4 v = ((const float4*)src)[i];
  ushort4 o;
  o.x = f2bf(v.x); o.y = f2bf(v.y); o.z = f2bf(v.z); o.w = f2bf(v.w);
  ((ushort4*)dst)[i] = o;
}

// ---------------------------------------------------------------------------
// Fused residual + LayerNorm; writes fp32 h and bf16 mirror hb.
// ---------------------------------------------------------------------------
__global__ __launch_bounds__(256) void ln_kernel(
    float* __restrict__ h, const float* __restrict__ a,
    const float* __restrict__ g, const float* __restrict__ bb,
    ushort_t* __restrict__ hb) {
  const int row = blockIdx.x * 4 + (threadIdx.x >> 6);
  const int lane = threadIdx.x & 63;
  const size_t base = (size_t)row * DMODEL;
  float v[8];
  float sum = 0.f, sq = 0.f;
#pragma unroll
  for (int i = 0; i < 8; ++i) {
    int col = lane + 64 * i;
    float x = h[base + col] + a[base + col];
    v[i] = x;
    sum += x;
    sq += x * x;
  }
#pragma unroll
  for (int off = 32; off; off >>= 1) {
    sum += __shfl_xor(sum, off);
    sq += __shfl_xor(sq, off);
  }
  float mean = sum * (1.f / 512.f);
  float var = fmaxf(sq * (1.f / 512.f) - mean * mean, 0.f);
  float rstd = 1.f / sqrtf(var + 1e-5f);
#pragma unroll
  for (int i = 0; i < 8; ++i) {
    int col = lane + 64 * i;
    float y = (v[i] - mean) * rstd * g[col] + bb[col];
    h[base + col] = y;
    hb[base + col] = f2bf(y);
  }
}

// ---------------------------------------------------------------------------
// ProbSparse attention v3.
// Phase 1 (per wave): S[16q][64k] via MFMA -> LDS s[16][SSTR].
// Phase 2 (wave w = query w): lane owns j = lane + 64*i (16 conflict-free
//   ds_read_b32). Exact 34th-largest via two-stage radix bisection:
//   stage A: 16-ballot counting, early-exit when count(>=ans) <= 64;
//   stage B: compact candidates to 1/lane (wave-local LDS scratch), finish
//   remaining bits at 1 ballot/bit. Compaction via ballot prefix-sum; no
//   atomics, no extra barrier (all phase-2 data is wave-private).
// ---------------------------------------------------------------------------
#define SSTR 1028

__global__ __launch_bounds__(1024) void attn_kernel(
    const ushort_t* __restrict__ Qb, const ushort_t* __restrict__ Kb,
    const ushort_t* __restrict__ Vb, ushort_t* __restrict__ Ob) {
  __shared__ float s[16 * SSTR];
  __shared__ int jlist[16][64];
  __shared__ float wlist[16][64];

  const int tid = threadIdx.x;
  const int q0 = blockIdx.x * 16;
  const int h = blockIdx.y;
  const int b = blockIdx.z;
  const int w = tid >> 6;
  const int lane = tid & 63;
  const int quad = lane >> 4, r16 = lane & 15;

  // ---- Phase 1: MFMA scores ----
  {
    const int j0 = w * 64;
    const ushort_t* qrow =
        Qb + (size_t)(b * SEQ + q0 + r16) * DMODEL + h * DK + quad * 8;
    short8 aq0 = *(const short8*)qrow;
    short8 aq1 = *(const short8*)(qrow + 32);

    float4v acc[4];
#pragma unroll
    for (int nt = 0; nt < 4; ++nt) {
      const ushort_t* krow =
          Kb + (size_t)(b * SEQ + j0 + nt * 16 + r16) * DMODEL + h * DK +
          quad * 8;
      short8 bk0 = *(const short8*)krow;
      short8 bk1 = *(const short8*)(krow + 32);
      float4v a = (float4v){0.f, 0.f, 0.f, 0.f};
      a = __builtin_amdgcn_mfma_f32_16x16x32_bf16(aq0, bk0, a, 0, 0, 0);
      a = __builtin_amdgcn_mfma_f32_16x16x32_bf16(aq1, bk1, a, 0, 0, 0);
      acc[nt] = a;
    }
#pragma unroll
    for (int nt = 0; nt < 4; ++nt)
#pragma unroll
      for (int reg = 0; reg < 4; ++reg)
        s[(quad * 4 + reg) * SSTR + j0 + nt * 16 + r16] =
            acc[nt][reg] * 0.125f;
  }
  __syncthreads();

  // ---- Phase 2 ----
  {
    // lane owns scores j = lane + 64*i : conflict-free stride-64 b32 reads
    float v[16];
    unsigned key[16];
    float mx = -1e30f;
#pragma unroll
    for (int i = 0; i < 16; ++i) {
      float f = s[w * SSTR + lane + 64 * i];
      v[i] = f;
      unsigned u = __float_as_uint(f);
      key[i] = (u & 0x80000000u) ? ~u : (u | 0x80000000u);
      mx = fmaxf(mx, f);
    }
#pragma unroll
    for (int off = 32; off; off >>= 1) mx = fmaxf(mx, __shfl_xor(mx, off));

    // stage A: full-set counting with early exit
    unsigned ans = 0u;
    int cge = 1024;
    int bit = 31;
    for (; bit >= 0 && cge > 64; --bit) {
      unsigned cand = ans | (1u << bit);
      int c = 0;
#pragma unroll
      for (int i = 0; i < 16; ++i)
        c += (int)__popcll(__ballot(key[i] >= cand));
      if (c >= U_TOP) { ans = cand; cge = c; }
    }

    // stage B: <=64 candidates, one per lane, 1 ballot/bit
    const unsigned long long lmask_lt = (1ull << lane) - 1ull;
    if (bit >= 0) {
      unsigned* tmp = (unsigned*)&wlist[w][0];  // wave-local scratch
      int base = 0;
#pragma unroll
      for (int i = 0; i < 16; ++i) {
        bool g = key[i] >= ans;
        unsigned long long mask = __ballot(g);
        if (g) tmp[base + (int)__popcll(mask & lmask_lt)] = key[i];
        base += (int)__popcll(mask);
      }
      unsigned ck = (lane < base) ? tmp[lane] : 0u;
      for (; bit >= 0; --bit) {
        unsigned cand = ans | (1u << bit);
        int c = (int)__popcll(__ballot(ck >= cand));
        if (c >= U_TOP) ans = cand;
      }
    }

    // compaction + softmax weights
    int total = 0;
    float zsum = 0.f;
#pragma unroll
    for (int i = 0; i < 16; ++i) {
      bool keep = key[i] >= ans;
      unsigned long long mask = __ballot(keep);
      if (keep) {
        float e = __expf(v[i] - mx);
        zsum += e;
        int pos = total + (int)__popcll(mask & lmask_lt);
        if (pos < 64) {
          jlist[w][pos] = lane + 64 * i;
          wlist[w][pos] = e;
        }
      }
      total += (int)__popcll(mask);
    }
#pragma unroll
    for (int off = 32; off; off >>= 1) zsum += __shfl_xor(zsum, off);

    int n = total < 64 ? total : 64;
    float zs = zsum;
    if (total > 64) {  // tie-overflow fallback (essentially never)
      zs = 0.f;
      for (int i = 0; i < n; ++i) zs += wlist[w][i];
    }

    // sparse PV: lane = output dim
    float o = 0.f;
    const ushort_t* vbase = Vb + (size_t)b * SEQ * DMODEL + h * DK;
    for (int i = 0; i < n; ++i) {
      int j = jlist[w][i];
      float wj = wlist[w][i];
      o += wj * bf2f(vbase[(size_t)j * DMODEL + lane]);
    }
    o /= zs;
    Ob[(size_t)(b * SEQ + q0 + w) * DMODEL + h * DK + lane] = f2bf(o);
  }
}

// ---------------------------------------------------------------------------
// Orchestration
// ---------------------------------------------------------------------------
extern "C" void kernel_launch(void* const* d_in, const int* in_sizes, int n_in,
                              void* d_out, int out_size, void* d_ws,
                              size_t ws_size, hipStream_t stream) {
  const float* x = (const float*)d_in[0];
  const float* W_emb = (const float*)d_in[1];
  const float* b_emb = (const float*)d_in[2];
  const float* Wq = (const float*)d_in[3];
  const float* bq = (const float*)d_in[4];
  const float* Wk = (const float*)d_in[5];
  const float* bk = (const float*)d_in[6];
  const float* Wv = (const float*)d_in[7];
  const float* bv = (const float*)d_in[8];
  const float* Wo = (const float*)d_in[9];
  const float* bo = (const float*)d_in[10];
  const float* ln1_g = (const float*)d_in[11];
  const float* ln1_b = (const float*)d_in[12];
  const float* W1 = (const float*)d_in[13];
  const float* b1 = (const float*)d_in[14];
  const float* W2 = (const float*)d_in[15];
  const float* b2 = (const float*)d_in[16];
  const float* ln2_g = (const float*)d_in[17];
  const float* ln2_b = (const float*)d_in[18];
  const float* W_dec = (const float*)d_in[19];
  const float* b_dec = (const float*)d_in[20];

  char* wsb = (char*)d_ws;
  float* h = (float*)wsb;
  ushort_t* qkv = (ushort_t*)(wsb + ((size_t)8 << 20));
  ushort_t* ffh = (ushort_t*)(wsb + ((size_t)8 << 20));
  ushort_t* ao = (ushort_t*)(wsb + ((size_t)24 << 20));
  float* t1 = (float*)(wsb + ((size_t)28 << 20));
  ushort_t* hb = (ushort_t*)(wsb + ((size_t)36 << 20));
  short* wt = (short*)(wsb + ((size_t)40 << 20));

  const size_t M1 = (size_t)ROWS * DMODEL;

  gemm_kernel<2><<<dim3(DMODEL / TN, ROWS / TM), 256, 0, stream>>>(
      x, W_emb, b_emb, h, ROWS, DMODEL, 128);
  f32_to_bf16_kernel<<<dim3((int)(M1 / 4 / 256)), 256, 0, stream>>>(h, hb);

  for (int i = 0; i < 3; ++i) {
    const size_t wsz = (size_t)DMODEL * DMODEL;
    convert_weights<<<dim3(3072), dim3(32, 8), 0, stream>>>(
        Wq + i * wsz, Wk + i * wsz, Wv + i * wsz, Wo + i * wsz,
        W1 + (size_t)i * DMODEL * DFF, W2 + (size_t)i * DFF * DMODEL, wt);

    // QKV batched (z=0,1,2): grid 8x32x3 = 768 blocks
    gemm_mfma<0, 1><<<dim3(8, 32, 3), 256, 0, stream>>>(
        hb, wt, bq + i * DMODEL, bk + i * DMODEL, bv + i * DMODEL, (void*)qkv,
        512, 512, 262144, 2097152);

    attn_kernel<<<dim3(SEQ / 16, NHEAD, BATCH), dim3(1024), 0, stream>>>(
        qkv, qkv + 2097152, qkv + 4194304, ao);

    gemm_mfma<0, 0><<<dim3(8, 32, 1), 256, 0, stream>>>(
        ao, wt + 786432, bo + i * DMODEL, bo + i * DMODEL, bo + i * DMODEL,
        (void*)t1, 512, 512, 0, 0);
    ln_kernel<<<dim3(ROWS / 4), 256, 0, stream>>>(
        h, t1, ln1_g + i * DMODEL, ln1_b + i * DMODEL, hb);

    gemm_mfma<1, 1><<<dim3(32, 32, 1), 256, 0, stream>>>(
        hb, wt + 1048576, b1 + i * DFF, b1 + i * DFF, b1 + i * DFF, (void*)ffh,
        512, 2048, 0, 0);
    gemm_mfma<0, 0><<<dim3(8, 32, 1), 256, 0, stream>>>(
        ffh, wt + 2097152, b2 + i * DMODEL, b2 + i * DMODEL, b2 + i * DMODEL,
        (void*)t1, 2048, 512, 0, 0);
    ln_kernel<<<dim3(ROWS / 4), 256, 0, stream>>>(
        h, t1, ln2_g + i * DMODEL, ln2_b + i * DMODEL, hb);
  }

  gemm_kernel<0><<<dim3(64 / TN, ROWS / TM), 256, 0, stream>>>(
      h, W_dec, b_dec, (float*)d_out, ROWS, 64, DMODEL);
}

// Round 5
// 637.181 us; speedup vs baseline: 3.2918x; 1.0728x over previous
//
#include <hip/hip_runtime.h>
#include <math.h>

#define SEQ 1024
#define BATCH 4
#define DMODEL 512
#define NHEAD 8
#define DK 64
#define DFF 2048
#define U_TOP 34
#define ROWS (BATCH * SEQ)

typedef unsigned short ushort_t;
typedef __attribute__((ext_vector_type(8))) short short8;
typedef __attribute__((ext_vector_type(4))) float float4v;

__device__ inline ushort_t f2bf(float f) {
  unsigned u = __float_as_uint(f);
  unsigned r = u + 0x7fffu + ((u >> 16) & 1u);
  return (ushort_t)(r >> 16);
}
__device__ inline float bf2f(ushort_t u) {
  return __uint_as_float((unsigned)u << 16);
}

__device__ inline void glds16(const void* g, void* l) {
  __builtin_amdgcn_global_load_lds(
      (const __attribute__((address_space(1))) unsigned int*)g,
      (__attribute__((address_space(3))) unsigned int*)l, 16, 0, 0);
}

// ---------------------------------------------------------------------------
// bf16 MFMA GEMM, tile 128(M) x 64(N), BK=32, 256 threads = 2x2 waves.
// C = A[M,K] @ Bt[N,K]^T + bias; z batches weights (QKV).
// EPI 0: none. EPI 2: v = v*sqrt(512) + pos-enc, dual-write fp32 C + bf16 hb2.
// ---------------------------------------------------------------------------
template <int RELU, int OUTBF16, int EPI>
__global__ __launch_bounds__(256) void gemm_mfma(
    const ushort_t* __restrict__ A, const short* __restrict__ Bt,
    const float* __restrict__ b0, const float* __restrict__ b1,
    const float* __restrict__ b2, void* __restrict__ Cout,
    ushort_t* __restrict__ hb2, int K, int N, int zWstride, int zCstride) {
  __shared__ short As[128 * 32];  // 8 KB
  __shared__ short Bs[64 * 32];   // 4 KB

  const int tid = threadIdx.x;
  const int lane = tid & 63, w = tid >> 6;
  const int wm = w >> 1, wn = w & 1;
  const int quad = lane >> 4, r16 = lane & 15;
  const int bm = blockIdx.y * 128, bn = blockIdx.x * 64;
  const int z = blockIdx.z;
  const short* Bz = Bt + (size_t)z * zWstride;
  const float* bias = (z == 0) ? b0 : (z == 1 ? b1 : b2);

  const int srow = lane >> 2, skseg = lane & 3;
  const ushort_t* Ag0 = A + (size_t)(bm + w * 32 + srow) * K + skseg * 8;
  const ushort_t* Ag1 = Ag0 + (size_t)16 * K;
  const short* Bg0 = Bz + (size_t)(bn + w * 16 + srow) * K + skseg * 8;
  short* lA0 = As + (w * 32) * 32;
  short* lA1 = As + (w * 32 + 16) * 32;
  short* lB0 = Bs + (w * 16) * 32;

  float4v acc[4][2];
#pragma unroll
  for (int m = 0; m < 4; ++m)
#pragma unroll
    for (int n = 0; n < 2; ++n) acc[m][n] = (float4v){0.f, 0.f, 0.f, 0.f};

  for (int k0 = 0; k0 < K; k0 += 32) {
    __syncthreads();
    glds16(Ag0 + k0, lA0);
    glds16(Ag1 + k0, lA1);
    glds16(Bg0 + k0, lB0);
    __syncthreads();

    short8 af[4], bfr[2];
#pragma unroll
    for (int m = 0; m < 4; ++m)
      af[m] = *(const short8*)&As[(wm * 64 + m * 16 + r16) * 32 + quad * 8];
#pragma unroll
    for (int n = 0; n < 2; ++n)
      bfr[n] = *(const short8*)&Bs[(wn * 32 + n * 16 + r16) * 32 + quad * 8];
#pragma unroll
    for (int m = 0; m < 4; ++m)
#pragma unroll
      for (int n = 0; n < 2; ++n)
        acc[m][n] = __builtin_amdgcn_mfma_f32_16x16x32_bf16(af[m], bfr[n],
                                                            acc[m][n], 0, 0, 0);
  }

  const float pe_c = (float)(-9.210340371976184 / 512.0);
  const float sqrtd = 22.62741699796952f;

  float bias_n[2];
#pragma unroll
  for (int n = 0; n < 2; ++n) bias_n[n] = bias[bn + wn * 32 + n * 16 + r16];

#pragma unroll
  for (int m = 0; m < 4; ++m) {
#pragma unroll
    for (int n = 0; n < 2; ++n) {
      int col = bn + wn * 32 + n * 16 + r16;
#pragma unroll
      for (int reg = 0; reg < 4; ++reg) {
        int row = bm + wm * 64 + m * 16 + quad * 4 + reg;
        float v = acc[m][n][reg] + bias_n[n];
        if (RELU) v = fmaxf(v, 0.f);
        if (EPI == 2) {
          int pos = row & (SEQ - 1);
          float e = __expf((float)(col & ~1) * pe_c);
          float arg = (float)pos * e;
          v = v * sqrtd + ((col & 1) ? __cosf(arg) : __sinf(arg));
        }
        if (OUTBF16) {
          ushort_t* C = (ushort_t*)Cout + (size_t)z * zCstride;
          C[(size_t)row * N + col] = f2bf(v);
        } else {
          float* C = (float*)Cout + (size_t)z * zCstride;
          C[(size_t)row * N + col] = v;
        }
        if (EPI == 2) hb2[(size_t)row * N + col] = f2bf(v);
      }
    }
  }
}

// ---------------------------------------------------------------------------
// Weight convert+transpose: W[K][N] f32 -> Wt[N][K] bf16 (6 weights/layer).
// ---------------------------------------------------------------------------
__global__ __launch_bounds__(256) void convert_weights(
    const float* __restrict__ Wq, const float* __restrict__ Wk,
    const float* __restrict__ Wv, const float* __restrict__ Wo,
    const float* __restrict__ W1, const float* __restrict__ W2,
    short* __restrict__ wt) {
  __shared__ float t[32][33];
  const int id = blockIdx.x;
  const float* src;
  short* dst;
  int K, N, tk, tn;
  if (id < 1024) {
    int wi = id >> 8, tile = id & 255;
    src = (wi == 0) ? Wq : (wi == 1) ? Wk : (wi == 2) ? Wv : Wo;
    dst = wt + wi * 262144;
    K = 512; N = 512; tk = tile >> 4; tn = tile & 15;
  } else if (id < 2048) {
    int tile = id - 1024;
    src = W1; dst = wt + 1048576;
    K = 512; N = 2048; tk = tile >> 6; tn = tile & 63;
  } else {
    int tile = id - 2048;
    src = W2; dst = wt + 2097152;
    K = 2048; N = 512; tk = tile >> 4; tn = tile & 15;
  }
  const int k0 = tk * 32, n0 = tn * 32;
  const int tx = threadIdx.x, ty = threadIdx.y;
#pragma unroll
  for (int i = 0; i < 4; ++i) {
    int r = ty + i * 8;
    t[r][tx] = src[(size_t)(k0 + r) * N + n0 + tx];
  }
  __syncthreads();
#pragma unroll
  for (int i = 0; i < 4; ++i) {
    int r = ty + i * 8;
    dst[(size_t)(n0 + r) * K + k0 + tx] = (short)f2bf(t[tx][r]);
  }
}

// W_emb [128x512] and W_dec [512x64] -> transposed bf16 (once per call).
__global__ __launch_bounds__(256) void convert_misc(
    const float* __restrict__ W_emb, const float* __restrict__ W_dec,
    short* __restrict__ wembT, short* __restrict__ wdecT) {
  __shared__ float t[32][33];
  int id = blockIdx.x;
  const float* src;
  short* dst;
  int K, N, tk, tn;
  if (id < 64) {
    src = W_emb; dst = wembT; K = 128; N = 512; tk = id >> 4; tn = id & 15;
  } else {
    id -= 64;
    src = W_dec; dst = wdecT; K = 512; N = 64; tk = id >> 1; tn = id & 1;
  }
  const int k0 = tk * 32, n0 = tn * 32;
  const int tx = threadIdx.x, ty = threadIdx.y;
#pragma unroll
  for (int i = 0; i < 4; ++i) {
    int r = ty + i * 8;
    t[r][tx] = src[(size_t)(k0 + r) * N + n0 + tx];
  }
  __syncthreads();
#pragma unroll
  for (int i = 0; i < 4; ++i) {
    int r = ty + i * 8;
    dst[(size_t)(n0 + r) * K + k0 + tx] = (short)f2bf(t[tx][r]);
  }
}

__global__ __launch_bounds__(256) void f32_to_bf16_kernel(
    const float* __restrict__ src, ushort_t* __restrict__ dst) {
  int i = blockIdx.x * blockDim.x + threadIdx.x;
  float4 v = ((const float4*)src)[i];
  ushort4 o;
  o.x = f2bf(v.x); o.y = f2bf(v.y); o.z = f2bf(v.z); o.w = f2bf(v.w);
  ((ushort4*)dst)[i] = o;
}

// ---------------------------------------------------------------------------
// Fused residual + LayerNorm; writes fp32 h and bf16 mirror hb.
// ---------------------------------------------------------------------------
__global__ __launch_bounds__(256) void ln_kernel(
    float* __restrict__ h, const float* __restrict__ a,
    const float* __restrict__ g, const float* __restrict__ bb,
    ushort_t* __restrict__ hb) {
  const int row = blockIdx.x * 4 + (threadIdx.x >> 6);
  const int lane = threadIdx.x & 63;
  const size_t base = (size_t)row * DMODEL;
  float v[8];
  float sum = 0.f, sq = 0.f;
#pragma unroll
  for (int i = 0; i < 8; ++i) {
    int col = lane + 64 * i;
    float x = h[base + col] + a[base + col];
    v[i] = x;
    sum += x;
    sq += x * x;
  }
#pragma unroll
  for (int off = 32; off; off >>= 1) {
    sum += __shfl_xor(sum, off);
    sq += __shfl_xor(sq, off);
  }
  float mean = sum * (1.f / 512.f);
  float var = fmaxf(sq * (1.f / 512.f) - mean * mean, 0.f);
  float rstd = 1.f / sqrtf(var + 1e-5f);
#pragma unroll
  for (int i = 0; i < 8; ++i) {
    int col = lane + 64 * i;
    float y = (v[i] - mean) * rstd * g[col] + bb[col];
    h[base + col] = y;
    hb[base + col] = f2bf(y);
  }
}

// ---------------------------------------------------------------------------
// ProbSparse attention v4.
// Phase 1 (per wave): S[16q][64k] via MFMA -> LDS s[16][SSTR].
// Phase 2 (wave w = query w): lane owns j = lane + 64*i (conflict-free b32).
//   Stage A: 16-ballot/bit radix bisection, exits at count<=64 OR count==34
//   (==34 means keep-set is exactly {key>=cand}; remaining bits irrelevant).
//   Single compaction of (key,j) candidates to one/lane; stage B finishes at
//   1 ballot/bit with the same ==34 early exit. Keep/exp/zsum/writes are one
//   ballot. PV unrolled x4 (independent gathers). No atomics, no barriers.
// ---------------------------------------------------------------------------
#define SSTR 1028

__global__ __launch_bounds__(1024) void attn_kernel(
    const ushort_t* __restrict__ Qb, const ushort_t* __restrict__ Kb,
    const ushort_t* __restrict__ Vb, ushort_t* __restrict__ Ob) {
  __shared__ float s[16 * SSTR];
  __shared__ int jlist[16][64];
  __shared__ float wlist[16][64];

  const int tid = threadIdx.x;
  const int q0 = blockIdx.x * 16;
  const int h = blockIdx.y;
  const int b = blockIdx.z;
  const int w = tid >> 6;
  const int lane = tid & 63;
  const int quad = lane >> 4, r16 = lane & 15;

  // ---- Phase 1: MFMA scores ----
  {
    const int j0 = w * 64;
    const ushort_t* qrow =
        Qb + (size_t)(b * SEQ + q0 + r16) * DMODEL + h * DK + quad * 8;
    short8 aq0 = *(const short8*)qrow;
    short8 aq1 = *(const short8*)(qrow + 32);

    float4v acc[4];
#pragma unroll
    for (int nt = 0; nt < 4; ++nt) {
      const ushort_t* krow =
          Kb + (size_t)(b * SEQ + j0 + nt * 16 + r16) * DMODEL + h * DK +
          quad * 8;
      short8 bk0 = *(const short8*)krow;
      short8 bk1 = *(const short8*)(krow + 32);
      float4v a = (float4v){0.f, 0.f, 0.f, 0.f};
      a = __builtin_amdgcn_mfma_f32_16x16x32_bf16(aq0, bk0, a, 0, 0, 0);
      a = __builtin_amdgcn_mfma_f32_16x16x32_bf16(aq1, bk1, a, 0, 0, 0);
      acc[nt] = a;
    }
#pragma unroll
    for (int nt = 0; nt < 4; ++nt)
#pragma unroll
      for (int reg = 0; reg < 4; ++reg)
        s[(quad * 4 + reg) * SSTR + j0 + nt * 16 + r16] =
            acc[nt][reg] * 0.125f;
  }
  __syncthreads();

  // ---- Phase 2 ----
  {
    float v[16];
    unsigned key[16];
    float mx = -1e30f;
#pragma unroll
    for (int i = 0; i < 16; ++i) {
      float f = s[w * SSTR + lane + 64 * i];
      v[i] = f;
      unsigned u = __float_as_uint(f);
      key[i] = (u & 0x80000000u) ? ~u : (u | 0x80000000u);
      mx = fmaxf(mx, f);
    }
#pragma unroll
    for (int off = 32; off; off >>= 1) mx = fmaxf(mx, __shfl_xor(mx, off));

    // stage A
    unsigned ans = 0u;
    int cge = 1024;
    int bit = 31;
    bool exact = false;
    while (bit >= 0 && cge > 64 && !exact) {
      unsigned cand = ans | (1u << bit);
      int c = 0;
#pragma unroll
      for (int i = 0; i < 16; ++i)
        c += (int)__popcll(__ballot(key[i] >= cand));
      if (c >= U_TOP) { ans = cand; cge = c; exact = (c == U_TOP); }
      --bit;
    }

    // single compaction of candidates {key >= ans} with (key, j) payload
    unsigned* tmpk = (unsigned*)&wlist[w][0];
    int* tmpj = &jlist[w][0];
    const unsigned long long lmask_lt = (1ull << lane) - 1ull;
    int base = 0;
#pragma unroll
    for (int i = 0; i < 16; ++i) {
      bool g = key[i] >= ans;
      unsigned long long mask = __ballot(g);
      if (g) {
        int p = base + (int)__popcll(mask & lmask_lt);
        if (p < 64) { tmpk[p] = key[i]; tmpj[p] = lane + 64 * i; }
      }
      base += (int)__popcll(mask);
    }
    if (base > 64) base = 64;
    unsigned ck = 0;
    int cj = 0;
    if (lane < base) { ck = tmpk[lane]; cj = tmpj[lane]; }

    // stage B: 1 ballot/bit
    while (bit >= 0 && !exact) {
      unsigned cand = ans | (1u << bit);
      int c = (int)__popcll(__ballot(ck >= cand));
      if (c >= U_TOP) { ans = cand; exact = (c == U_TOP); }
      --bit;
    }

    // final keep set, weights, compaction (one ballot)
    bool keep = (lane < base) && (ck >= ans);
    unsigned long long kmask = __ballot(keep);
    int n = (int)__popcll(kmask);
    float f = (ck & 0x80000000u) ? __uint_as_float(ck ^ 0x80000000u)
                                 : __uint_as_float(~ck);
    float e = keep ? __expf(f - mx) : 0.f;
    float zsum = e;
#pragma unroll
    for (int off = 32; off; off >>= 1) zsum += __shfl_xor(zsum, off);
    int pos = (int)__popcll(kmask & lmask_lt);
    if (keep) { jlist[w][pos] = cj; wlist[w][pos] = e; }

    // sparse PV, unroll x4 (independent gathers)
    const ushort_t* vbase = Vb + (size_t)b * SEQ * DMODEL + h * DK;
    float o = 0.f;
    int i = 0;
    for (; i + 4 <= n; i += 4) {
      int j0 = jlist[w][i], j1 = jlist[w][i + 1];
      int j2 = jlist[w][i + 2], j3 = jlist[w][i + 3];
      float w0 = wlist[w][i], w1 = wlist[w][i + 1];
      float w2 = wlist[w][i + 2], w3 = wlist[w][i + 3];
      float p0 = bf2f(vbase[(size_t)j0 * DMODEL + lane]);
      float p1 = bf2f(vbase[(size_t)j1 * DMODEL + lane]);
      float p2 = bf2f(vbase[(size_t)j2 * DMODEL + lane]);
      float p3 = bf2f(vbase[(size_t)j3 * DMODEL + lane]);
      o += w0 * p0 + w1 * p1 + w2 * p2 + w3 * p3;
    }
    for (; i < n; ++i)
      o += wlist[w][i] * bf2f(vbase[(size_t)jlist[w][i] * DMODEL + lane]);
    o /= zsum;
    Ob[(size_t)(b * SEQ + q0 + w) * DMODEL + h * DK + lane] = f2bf(o);
  }
}

// ---------------------------------------------------------------------------
// Orchestration
// ---------------------------------------------------------------------------
extern "C" void kernel_launch(void* const* d_in, const int* in_sizes, int n_in,
                              void* d_out, int out_size, void* d_ws,
                              size_t ws_size, hipStream_t stream) {
  const float* x = (const float*)d_in[0];
  const float* W_emb = (const float*)d_in[1];
  const float* b_emb = (const float*)d_in[2];
  const float* Wq = (const float*)d_in[3];
  const float* bq = (const float*)d_in[4];
  const float* Wk = (const float*)d_in[5];
  const float* bk = (const float*)d_in[6];
  const float* Wv = (const float*)d_in[7];
  const float* bv = (const float*)d_in[8];
  const float* Wo = (const float*)d_in[9];
  const float* bo = (const float*)d_in[10];
  const float* ln1_g = (const float*)d_in[11];
  const float* ln1_b = (const float*)d_in[12];
  const float* W1 = (const float*)d_in[13];
  const float* b1 = (const float*)d_in[14];
  const float* W2 = (const float*)d_in[15];
  const float* b2 = (const float*)d_in[16];
  const float* ln2_g = (const float*)d_in[17];
  const float* ln2_b = (const float*)d_in[18];
  const float* W_dec = (const float*)d_in[19];
  const float* b_dec = (const float*)d_in[20];

  // ws layout (bytes): [0,8M) h f32 | [8M,24M) qkv/ffh bf16 (also xb at embed
  // time) | [24M,28M) ao bf16 | [28M,36M) t1 f32 | [36M,40M) hb bf16 |
  // [40M,~46.2M) wt bf16: per-layer 3145728 el + wembT @3145728 (65536) +
  // wdecT @3211264 (32768).
  char* wsb = (char*)d_ws;
  float* h = (float*)wsb;
  ushort_t* qkv = (ushort_t*)(wsb + ((size_t)8 << 20));
  ushort_t* xb = (ushort_t*)(wsb + ((size_t)8 << 20));
  ushort_t* ffh = (ushort_t*)(wsb + ((size_t)8 << 20));
  ushort_t* ao = (ushort_t*)(wsb + ((size_t)24 << 20));
  float* t1 = (float*)(wsb + ((size_t)28 << 20));
  ushort_t* hb = (ushort_t*)(wsb + ((size_t)36 << 20));
  short* wt = (short*)(wsb + ((size_t)40 << 20));
  short* wembT = wt + 3145728;
  short* wdecT = wt + 3211264;

  // x -> bf16 (4096x128), misc weights, embed via MFMA (EPI=2: PE + dual out)
  f32_to_bf16_kernel<<<dim3(512), 256, 0, stream>>>(x, xb);
  convert_misc<<<dim3(96), dim3(32, 8), 0, stream>>>(W_emb, W_dec, wembT,
                                                     wdecT);
  gemm_mfma<0, 0, 2><<<dim3(8, 32), 256, 0, stream>>>(
      xb, wembT, b_emb, b_emb, b_emb, (void*)h, hb, 128, 512, 0, 0);

  for (int i = 0; i < 3; ++i) {
    const size_t wsz = (size_t)DMODEL * DMODEL;
    convert_weights<<<dim3(3072), dim3(32, 8), 0, stream>>>(
        Wq + i * wsz, Wk + i * wsz, Wv + i * wsz, Wo + i * wsz,
        W1 + (size_t)i * DMODEL * DFF, W2 + (size_t)i * DFF * DMODEL, wt);

    gemm_mfma<0, 1, 0><<<dim3(8, 32, 3), 256, 0, stream>>>(
        hb, wt, bq + i * DMODEL, bk + i * DMODEL, bv + i * DMODEL, (void*)qkv,
        nullptr, 512, 512, 262144, 2097152);

    attn_kernel<<<dim3(SEQ / 16, NHEAD, BATCH), dim3(1024), 0, stream>>>(
        qkv, qkv + 2097152, qkv + 4194304, ao);

    gemm_mfma<0, 0, 0><<<dim3(8, 32, 1), 256, 0, stream>>>(
        ao, wt + 786432, bo + i * DMODEL, bo + i * DMODEL, bo + i * DMODEL,
        (void*)t1, nullptr, 512, 512, 0, 0);
    ln_kernel<<<dim3(ROWS / 4), 256, 0, stream>>>(
        h, t1, ln1_g + i * DMODEL, ln1_b + i * DMODEL, hb);

    gemm_mfma<1, 1, 0><<<dim3(32, 32, 1), 256, 0, stream>>>(
        hb, wt + 1048576, b1 + i * DFF, b1 + i * DFF, b1 + i * DFF, (void*)ffh,
        nullptr, 512, 2048, 0, 0);
    gemm_mfma<0, 0, 0><<<dim3(8, 32, 1), 256, 0, stream>>>(
        ffh, wt + 2097152, b2 + i * DMODEL, b2 + i * DMODEL, b2 + i * DMODEL,
        (void*)t1, nullptr, 2048, 512, 0, 0);
    ln_kernel<<<dim3(ROWS / 4), 256, 0, stream>>>(
        h, t1, ln2_g + i * DMODEL, ln2_b + i * DMODEL, hb);
  }

  gemm_mfma<0, 0, 0><<<dim3(1, 32), 256, 0, stream>>>(
      hb, wdecT, b_dec, b_dec, b_dec, d_out, nullptr, 512, 64, 0, 0);
}

// Round 6
// 575.114 us; speedup vs baseline: 3.6471x; 1.1079x over previous
//
#include <hip/hip_runtime.h>
#include <math.h>

#define SEQ 1024
#define BATCH 4
#define DMODEL 512
#define NHEAD 8
#define DK 64
#define DFF 2048
#define U_TOP 34
#define ROWS (BATCH * SEQ)

typedef unsigned short ushort_t;
typedef __attribute__((ext_vector_type(8))) short short8;
typedef __attribute__((ext_vector_type(4))) float float4v;

__device__ inline ushort_t f2bf(float f) {
  unsigned u = __float_as_uint(f);
  unsigned r = u + 0x7fffu + ((u >> 16) & 1u);
  return (ushort_t)(r >> 16);
}
__device__ inline float bf2f(ushort_t u) {
  return __uint_as_float((unsigned)u << 16);
}
// ordered-uint key -> float (inverse of f -> sign?~u:u|0x80000000)
__device__ inline float keyinv(unsigned cand) {
  unsigned fb = (cand & 0x80000000u) ? (cand ^ 0x80000000u) : ~cand;
  return __uint_as_float(fb);
}

__device__ inline void glds16(const void* g, void* l) {
  __builtin_amdgcn_global_load_lds(
      (const __attribute__((address_space(1))) unsigned int*)g,
      (__attribute__((address_space(3))) unsigned int*)l, 16, 0, 0);
}

// ---------------------------------------------------------------------------
// bf16 MFMA GEMM, tile 64x64, BK=32, 256 threads = 2x2 waves, 12 KB LDS.
// C = A[M,K] @ Bt[N,K]^T + bias (+ optional residual add from bf16 Cadd).
// EPI 0: none. EPI 2: v = v*sqrt(512) + positional encoding (embed).
// z batches weight matrices (QKV).
// ---------------------------------------------------------------------------
template <int RELU, int OUTBF16, int EPI, int ADDC>
__global__ __launch_bounds__(256) void gemm64(
    const ushort_t* __restrict__ A, const short* __restrict__ Bt,
    const float* __restrict__ b0, const float* __restrict__ b1,
    const float* __restrict__ b2, void* __restrict__ Cout,
    const ushort_t* __restrict__ Cadd, int K, int N, int zWstride,
    int zCstride) {
  __shared__ short As[64 * 32];  // 4 KB
  __shared__ short Bs[64 * 32];  // 4 KB

  const int tid = threadIdx.x;
  const int lane = tid & 63, w = tid >> 6;
  const int wm = w >> 1, wn = w & 1;
  const int quad = lane >> 4, r16 = lane & 15;
  const int bm = blockIdx.y * 64, bn = blockIdx.x * 64;
  const int z = blockIdx.z;
  const short* Bz = Bt + (size_t)z * zWstride;
  const float* bias = (z == 0) ? b0 : (z == 1 ? b1 : b2);

  // staging: thread t -> row t>>2, 16B k-seg t&3 ; LDS offset t*16B
  const int srow = tid >> 2, skseg = tid & 3;
  const ushort_t* Ag = A + (size_t)(bm + srow) * K + skseg * 8;
  const short* Bg = Bz + (size_t)(bn + srow) * K + skseg * 8;
  short* lA = As + w * 512;  // wave-uniform base; HW adds lane*16B
  short* lB = Bs + w * 512;

  float4v acc[2][2];
#pragma unroll
  for (int m = 0; m < 2; ++m)
#pragma unroll
    for (int n = 0; n < 2; ++n) acc[m][n] = (float4v){0.f, 0.f, 0.f, 0.f};

  for (int k0 = 0; k0 < K; k0 += 32) {
    __syncthreads();
    glds16(Ag + k0, lA);
    glds16(Bg + k0, lB);
    __syncthreads();

    short8 af[2], bfr[2];
#pragma unroll
    for (int m = 0; m < 2; ++m)
      af[m] = *(const short8*)&As[(wm * 32 + m * 16 + r16) * 32 + quad * 8];
#pragma unroll
    for (int n = 0; n < 2; ++n)
      bfr[n] = *(const short8*)&Bs[(wn * 32 + n * 16 + r16) * 32 + quad * 8];
#pragma unroll
    for (int m = 0; m < 2; ++m)
#pragma unroll
      for (int n = 0; n < 2; ++n)
        acc[m][n] = __builtin_amdgcn_mfma_f32_16x16x32_bf16(af[m], bfr[n],
                                                            acc[m][n], 0, 0, 0);
  }

  const float pe_c = (float)(-9.210340371976184 / 512.0);
  const float sqrtd = 22.62741699796952f;

  float bias_n[2];
#pragma unroll
  for (int n = 0; n < 2; ++n) bias_n[n] = bias[bn + wn * 32 + n * 16 + r16];

#pragma unroll
  for (int m = 0; m < 2; ++m) {
#pragma unroll
    for (int n = 0; n < 2; ++n) {
      int col = bn + wn * 32 + n * 16 + r16;
#pragma unroll
      for (int reg = 0; reg < 4; ++reg) {
        int row = bm + wm * 32 + m * 16 + quad * 4 + reg;
        float v = acc[m][n][reg] + bias_n[n];
        if (RELU) v = fmaxf(v, 0.f);
        if (EPI == 2) {
          int pos = row & (SEQ - 1);
          float e = __expf((float)(col & ~1) * pe_c);
          float arg = (float)pos * e;
          v = v * sqrtd + ((col & 1) ? __cosf(arg) : __sinf(arg));
        }
        if (ADDC) v += bf2f(Cadd[(size_t)row * N + col]);
        if (OUTBF16) {
          ushort_t* C = (ushort_t*)Cout + (size_t)z * zCstride;
          C[(size_t)row * N + col] = f2bf(v);
        } else {
          float* C = (float*)Cout + (size_t)z * zCstride;
          C[(size_t)row * N + col] = v;
        }
      }
    }
  }
}

// ---------------------------------------------------------------------------
// All weights (3 layers + emb + dec): W[K][N] f32 -> Wt[N][K] bf16, 1 launch.
// Per-layer element offsets in wt: Wq 0, Wk 262144, Wv 524288, Wo 786432,
// W1 1048576, W2 2097152; layer stride 3145728; emb @9437184, dec @9502720.
// ---------------------------------------------------------------------------
__global__ __launch_bounds__(256) void convert_all(
    const float* __restrict__ Wq, const float* __restrict__ Wk,
    const float* __restrict__ Wv, const float* __restrict__ Wo,
    const float* __restrict__ W1, const float* __restrict__ W2,
    const float* __restrict__ W_emb, const float* __restrict__ W_dec,
    short* __restrict__ wt) {
  __shared__ float t[32][33];
  int id = blockIdx.x;
  const float* src;
  short* dst;
  int K, N, tk, tn;
  if (id < 9216) {
    int lay = id / 3072, r = id % 3072;
    short* wl = wt + (size_t)lay * 3145728;
    const size_t wsz = 512 * 512;
    if (r < 1024) {
      int wi = r >> 8, tile = r & 255;
      const float* base = (wi == 0) ? Wq : (wi == 1) ? Wk : (wi == 2) ? Wv : Wo;
      src = base + lay * wsz;
      dst = wl + wi * 262144;
      K = 512; N = 512; tk = tile >> 4; tn = tile & 15;
    } else if (r < 2048) {
      int tile = r - 1024;
      src = W1 + (size_t)lay * 512 * 2048;
      dst = wl + 1048576;
      K = 512; N = 2048; tk = tile >> 6; tn = tile & 63;
    } else {
      int tile = r - 2048;
      src = W2 + (size_t)lay * 2048 * 512;
      dst = wl + 2097152;
      K = 2048; N = 512; tk = tile >> 4; tn = tile & 15;
    }
  } else {
    int r = id - 9216;
    if (r < 64) {
      src = W_emb; dst = wt + 9437184; K = 128; N = 512; tk = r >> 4; tn = r & 15;
    } else {
      r -= 64;
      src = W_dec; dst = wt + 9502720; K = 512; N = 64; tk = r >> 1; tn = r & 1;
    }
  }
  const int k0 = tk * 32, n0 = tn * 32;
  const int tx = threadIdx.x, ty = threadIdx.y;
#pragma unroll
  for (int i = 0; i < 4; ++i) {
    int r = ty + i * 8;
    t[r][tx] = src[(size_t)(k0 + r) * N + n0 + tx];
  }
  __syncthreads();
#pragma unroll
  for (int i = 0; i < 4; ++i) {
    int r = ty + i * 8;
    dst[(size_t)(n0 + r) * K + k0 + tx] = (short)f2bf(t[tx][r]);
  }
}

__global__ __launch_bounds__(256) void f32_to_bf16_kernel(
    const float* __restrict__ src, ushort_t* __restrict__ dst) {
  int i = blockIdx.x * blockDim.x + threadIdx.x;
  float4 v = ((const float4*)src)[i];
  ushort4 o;
  o.x = f2bf(v.x); o.y = f2bf(v.y); o.z = f2bf(v.z); o.w = f2bf(v.w);
  ((ushort4*)dst)[i] = o;
}

// ---------------------------------------------------------------------------
// LayerNorm on pre-summed bf16 input: hb[row] = LN(t1b[row]) * g + b.
// One wave per row; lane owns 8 contiguous cols (16B vector load/store).
// ---------------------------------------------------------------------------
__global__ __launch_bounds__(256) void ln_kernel(
    const ushort_t* __restrict__ t1b, const float* __restrict__ g,
    const float* __restrict__ bb, ushort_t* __restrict__ hb) {
  const int row = blockIdx.x * 4 + (threadIdx.x >> 6);
  const int lane = threadIdx.x & 63;
  const size_t base = (size_t)row * DMODEL + lane * 8;
  uint4 raw = *(const uint4*)(t1b + base);
  unsigned rr[4] = {raw.x, raw.y, raw.z, raw.w};
  float v[8];
#pragma unroll
  for (int k = 0; k < 4; ++k) {
    v[2 * k] = bf2f((ushort_t)(rr[k] & 0xffff));
    v[2 * k + 1] = bf2f((ushort_t)(rr[k] >> 16));
  }
  float sum = 0.f, sq = 0.f;
#pragma unroll
  for (int k = 0; k < 8; ++k) { sum += v[k]; sq += v[k] * v[k]; }
#pragma unroll
  for (int off = 32; off; off >>= 1) {
    sum += __shfl_xor(sum, off);
    sq += __shfl_xor(sq, off);
  }
  float mean = sum * (1.f / 512.f);
  float var = fmaxf(sq * (1.f / 512.f) - mean * mean, 0.f);
  float rstd = 1.f / sqrtf(var + 1e-5f);
  float4 g0 = *(const float4*)(g + lane * 8);
  float4 g1 = *(const float4*)(g + lane * 8 + 4);
  float4 c0 = *(const float4*)(bb + lane * 8);
  float4 c1 = *(const float4*)(bb + lane * 8 + 4);
  float gg[8] = {g0.x, g0.y, g0.z, g0.w, g1.x, g1.y, g1.z, g1.w};
  float cc[8] = {c0.x, c0.y, c0.z, c0.w, c1.x, c1.y, c1.z, c1.w};
  uint4 out;
  unsigned* op = (unsigned*)&out;
#pragma unroll
  for (int k = 0; k < 4; ++k) {
    float y0 = (v[2 * k] - mean) * rstd * gg[2 * k] + cc[2 * k];
    float y1 = (v[2 * k + 1] - mean) * rstd * gg[2 * k + 1] + cc[2 * k + 1];
    op[k] = (unsigned)f2bf(y0) | ((unsigned)f2bf(y1) << 16);
  }
  *(uint4*)(hb + base) = out;
}

// ---------------------------------------------------------------------------
// ProbSparse attention v5.
// Phase 1 (per wave): S[16q][64k] via MFMA -> LDS s[16][SSTR] (fp32 scores).
// Phase 2 (wave w = query w): lane owns j = lane + 64*i.
//   All threshold compares in FLOAT domain (v_cmp_ge_f32 vs scalar keyinv()).
//   T-prefilter: exact 34th-largest of the 64 lane maxima (1 cmp/bit) is a
//   lower bound on the global 34th; one 16-ballot count pass; if <=64
//   candidates (typical), compact once and finish with 1-cmp/bit stage B.
//   Rare fallback (>64): classic 16-cmp/bit stage A. Keep set {v >= thr}
//   keeps ties, matching reference `scores < kth -> -inf` semantics.
// __launch_bounds__(1024, 8): 2 blocks/CU (LDS limit), 64-VGPR budget ->
// prevents the 32-VGPR scratch-spill the default heuristic chose (R5).
// ---------------------------------------------------------------------------
#define SSTR 1028

__global__ __launch_bounds__(1024, 8) void attn_kernel(
    const ushort_t* __restrict__ Qb, const ushort_t* __restrict__ Kb,
    const ushort_t* __restrict__ Vb, ushort_t* __restrict__ Ob) {
  __shared__ float s[16 * SSTR];
  __shared__ int jlist[16][64];
  __shared__ float wlist[16][64];

  const int tid = threadIdx.x;
  const int q0 = blockIdx.x * 16;
  const int h = blockIdx.y;
  const int b = blockIdx.z;
  const int w = tid >> 6;
  const int lane = tid & 63;
  const int quad = lane >> 4, r16 = lane & 15;

  // ---- Phase 1: MFMA scores ----
  {
    const int j0 = w * 64;
    const ushort_t* qrow =
        Qb + (size_t)(b * SEQ + q0 + r16) * DMODEL + h * DK + quad * 8;
    short8 aq0 = *(const short8*)qrow;
    short8 aq1 = *(const short8*)(qrow + 32);

    float4v acc[4];
#pragma unroll
    for (int nt = 0; nt < 4; ++nt) {
      const ushort_t* krow =
          Kb + (size_t)(b * SEQ + j0 + nt * 16 + r16) * DMODEL + h * DK +
          quad * 8;
      short8 bk0 = *(const short8*)krow;
      short8 bk1 = *(const short8*)(krow + 32);
      float4v a = (float4v){0.f, 0.f, 0.f, 0.f};
      a = __builtin_amdgcn_mfma_f32_16x16x32_bf16(aq0, bk0, a, 0, 0, 0);
      a = __builtin_amdgcn_mfma_f32_16x16x32_bf16(aq1, bk1, a, 0, 0, 0);
      acc[nt] = a;
    }
#pragma unroll
    for (int nt = 0; nt < 4; ++nt)
#pragma unroll
      for (int reg = 0; reg < 4; ++reg)
        s[(quad * 4 + reg) * SSTR + j0 + nt * 16 + r16] =
            acc[nt][reg] * 0.125f;
  }
  __syncthreads();

  // ---- Phase 2 ----
  {
    float v[16];
    float lmax = -1e30f;
#pragma unroll
    for (int i = 0; i < 16; ++i) {
      float f = s[w * SSTR + lane + 64 * i];
      v[i] = f;
      lmax = fmaxf(lmax, f);
    }
    float mx = lmax;
#pragma unroll
    for (int off = 32; off; off >>= 1) mx = fmaxf(mx, __shfl_xor(mx, off));

    // T-prefilter: exact 34th-largest of lane maxima (1 cmp/bit)
    unsigned ansT = 0u;
    {
      bool ex = false;
      for (int bit = 31; bit >= 0 && !ex; --bit) {
        unsigned cand = ansT | (1u << bit);
        float fc = keyinv(cand);
        int c = (int)__popcll(__ballot(lmax >= fc));
        if (c >= U_TOP) { ansT = cand; ex = (c == U_TOP); }
      }
    }
    const float fT = keyinv(ansT);

    // global candidate count at T
    int total = 0;
#pragma unroll
    for (int i = 0; i < 16; ++i)
      total += (int)__popcll(__ballot(v[i] >= fT));

    const unsigned long long lmask_lt = (1ull << lane) - 1ull;
    float* tmpv = &wlist[w][0];
    int* tmpj = &jlist[w][0];
    int ncand;
    if (total <= 64) {
      int basec = 0;
#pragma unroll
      for (int i = 0; i < 16; ++i) {
        bool gk = v[i] >= fT;
        unsigned long long mask = __ballot(gk);
        if (gk) {
          int p = basec + (int)__popcll(mask & lmask_lt);
          tmpv[p] = v[i];
          tmpj[p] = lane + 64 * i;
        }
        basec += (int)__popcll(mask);
      }
      ncand = basec;
    } else {
      // fallback: classic stage A (rare)
      unsigned ans = 0u;
      int cge = 1024, bit = 31;
      bool ex = false;
      while (bit >= 0 && cge > 64 && !ex) {
        unsigned cand = ans | (1u << bit);
        float fc = keyinv(cand);
        int c = 0;
#pragma unroll
        for (int i = 0; i < 16; ++i) c += (int)__popcll(__ballot(v[i] >= fc));
        if (c >= U_TOP) { ans = cand; cge = c; ex = (c == U_TOP); }
        --bit;
      }
      float fa = keyinv(ans);
      int basec = 0;
#pragma unroll
      for (int i = 0; i < 16; ++i) {
        bool gk = v[i] >= fa;
        unsigned long long mask = __ballot(gk);
        if (gk) {
          int p = basec + (int)__popcll(mask & lmask_lt);
          if (p < 64) { tmpv[p] = v[i]; tmpj[p] = lane + 64 * i; }
        }
        basec += (int)__popcll(mask);
      }
      ncand = basec > 64 ? 64 : basec;
    }

    // one candidate per lane
    float cf = (lane < ncand) ? tmpv[lane] : -3.4e38f;
    int cj = (lane < ncand) ? tmpj[lane] : 0;

    // stage B: exact 34th-largest over candidates, 1 cmp/bit
    unsigned ansB = 0u;
    {
      bool ex = false;
      for (int bit = 31; bit >= 0 && !ex; --bit) {
        unsigned cand = ansB | (1u << bit);
        float fc = keyinv(cand);
        int c = (int)__popcll(__ballot(cf >= fc));
        if (c >= U_TOP) { ansB = cand; ex = (c == U_TOP); }
      }
    }
    const float thr = keyinv(ansB);

    // keep set, weights, final compaction
    bool keep = cf >= thr;
    unsigned long long kmask = __ballot(keep);
    int n = (int)__popcll(kmask);
    float e = keep ? __expf(cf - mx) : 0.f;
    float zsum = e;
#pragma unroll
    for (int off = 32; off; off >>= 1) zsum += __shfl_xor(zsum, off);
    int pos = (int)__popcll(kmask & lmask_lt);
    if (keep) { jlist[w][pos] = cj; wlist[w][pos] = e; }

    // sparse PV, unroll x4
    const ushort_t* vbase = Vb + (size_t)b * SEQ * DMODEL + h * DK;
    float o = 0.f;
    int i = 0;
    for (; i + 4 <= n; i += 4) {
      int j0 = jlist[w][i], j1 = jlist[w][i + 1];
      int j2 = jlist[w][i + 2], j3 = jlist[w][i + 3];
      float w0 = wlist[w][i], w1 = wlist[w][i + 1];
      float w2 = wlist[w][i + 2], w3 = wlist[w][i + 3];
      float p0 = bf2f(vbase[(size_t)j0 * DMODEL + lane]);
      float p1 = bf2f(vbase[(size_t)j1 * DMODEL + lane]);
      float p2 = bf2f(vbase[(size_t)j2 * DMODEL + lane]);
      float p3 = bf2f(vbase[(size_t)j3 * DMODEL + lane]);
      o += w0 * p0 + w1 * p1 + w2 * p2 + w3 * p3;
    }
    for (; i < n; ++i)
      o += wlist[w][i] * bf2f(vbase[(size_t)jlist[w][i] * DMODEL + lane]);
    o /= zsum;
    Ob[(size_t)(b * SEQ + q0 + w) * DMODEL + h * DK + lane] = f2bf(o);
  }
}

// ---------------------------------------------------------------------------
// Orchestration.  ws layout (MiB): ffh [0,16) (qkv q@0,k@4,v@8 alias it) |
// ao [16,20) (xb aliases [16,17) pre-loop) | t1b [20,24) | hb [24,28) |
// wt [28, 46.19) bf16 transposed weights (3 layers + emb + dec).
// ---------------------------------------------------------------------------
extern "C" void kernel_launch(void* const* d_in, const int* in_sizes, int n_in,
                              void* d_out, int out_size, void* d_ws,
                              size_t ws_size, hipStream_t stream) {
  const float* x = (const float*)d_in[0];
  const float* W_emb = (const float*)d_in[1];
  const float* b_emb = (const float*)d_in[2];
  const float* Wq = (const float*)d_in[3];
  const float* bq = (const float*)d_in[4];
  const float* Wk = (const float*)d_in[5];
  const float* bk = (const float*)d_in[6];
  const float* Wv = (const float*)d_in[7];
  const float* bv = (const float*)d_in[8];
  const float* Wo = (const float*)d_in[9];
  const float* bo = (const float*)d_in[10];
  const float* ln1_g = (const float*)d_in[11];
  const float* ln1_b = (const float*)d_in[12];
  const float* W1 = (const float*)d_in[13];
  const float* b1 = (const float*)d_in[14];
  const float* W2 = (const float*)d_in[15];
  const float* b2 = (const float*)d_in[16];
  const float* ln2_g = (const float*)d_in[17];
  const float* ln2_b = (const float*)d_in[18];
  const float* W_dec = (const float*)d_in[19];
  const float* b_dec = (const float*)d_in[20];

  char* wsb = (char*)d_ws;
  ushort_t* qkv = (ushort_t*)wsb;
  ushort_t* ffh = (ushort_t*)wsb;
  ushort_t* ao = (ushort_t*)(wsb + ((size_t)16 << 20));
  ushort_t* xb = (ushort_t*)(wsb + ((size_t)16 << 20));
  ushort_t* t1b = (ushort_t*)(wsb + ((size_t)20 << 20));
  ushort_t* hb = (ushort_t*)(wsb + ((size_t)24 << 20));
  short* wt = (short*)(wsb + ((size_t)28 << 20));
  short* wembT = wt + 9437184;
  short* wdecT = wt + 9502720;

  f32_to_bf16_kernel<<<dim3(512), 256, 0, stream>>>(x, xb);
  convert_all<<<dim3(9312), dim3(32, 8), 0, stream>>>(Wq, Wk, Wv, Wo, W1, W2,
                                                      W_emb, W_dec, wt);
  // embed: hb = bf16((xb @ W_emb + b_emb)*sqrt(512) + PE)
  gemm64<0, 1, 2, 0><<<dim3(8, 64), 256, 0, stream>>>(
      xb, wembT, b_emb, b_emb, b_emb, (void*)hb, nullptr, 128, 512, 0, 0);

  for (int i = 0; i < 3; ++i) {
    short* wtL = wt + (size_t)i * 3145728;

    gemm64<0, 1, 0, 0><<<dim3(8, 64, 3), 256, 0, stream>>>(
        hb, wtL, bq + i * DMODEL, bk + i * DMODEL, bv + i * DMODEL,
        (void*)qkv, nullptr, 512, 512, 262144, 2097152);

    attn_kernel<<<dim3(SEQ / 16, NHEAD, BATCH), dim3(1024), 0, stream>>>(
        qkv, qkv + 2097152, qkv + 4194304, ao);

    // t1b = ao @ Wo + bo + hb   (residual fused)
    gemm64<0, 1, 0, 1><<<dim3(8, 64), 256, 0, stream>>>(
        ao, wtL + 786432, bo + i * DMODEL, bo + i * DMODEL, bo + i * DMODEL,
        (void*)t1b, hb, 512, 512, 0, 0);
    ln_kernel<<<dim3(ROWS / 4), 256, 0, stream>>>(
        t1b, ln1_g + i * DMODEL, ln1_b + i * DMODEL, hb);

    gemm64<1, 1, 0, 0><<<dim3(32, 64), 256, 0, stream>>>(
        hb, wtL + 1048576, b1 + i * DFF, b1 + i * DFF, b1 + i * DFF,
        (void*)ffh, nullptr, 512, 2048, 0, 0);
    // t1b = ffh @ W2 + b2 + hb  (residual fused)
    gemm64<0, 1, 0, 1><<<dim3(8, 64), 256, 0, stream>>>(
        ffh, wtL + 2097152, b2 + i * DMODEL, b2 + i * DMODEL, b2 + i * DMODEL,
        (void*)t1b, hb, 2048, 512, 0, 0);
    ln_kernel<<<dim3(ROWS / 4), 256, 0, stream>>>(
        t1b, ln2_g + i * DMODEL, ln2_b + i * DMODEL, hb);
  }

  gemm64<0, 0, 0, 0><<<dim3(1, 64), 256, 0, stream>>>(
      hb, wdecT, b_dec, b_dec, b_dec, d_out, nullptr, 512, 64, 0, 0);
}